// Round 2
// baseline (4462.874 us; speedup 1.0000x reference)
//
#include <hip/hip_runtime.h>
#include <hip/hip_bf16.h>
#include <math.h>

#define B_ 4
#define S_ 4096
#define D_ 512
#define H_ 8
#define NC_ 64
#define M_ (B_*S_)     // 16384
#define BH_ (B_*H_)    // 32

// ---------------------------------------------------------------------------
// Tiled f32 GEMM: C = A[M,K] * B[K,N] (+bias)(+relu)(+f32 residual)
// OUTMODE: 0 = f32 row-major [M,N], 1 = f32 qkv-scatter [B,H,S,64]
// RES:     0 = none, 1 = f32 residual row-major [M,N]
// ---------------------------------------------------------------------------
template<int OUTMODE, int RES, bool BIAS, bool RELU>
__global__ __launch_bounds__(256) void gemm_k(
    const float* __restrict__ A, const float* __restrict__ Bw,
    const float* __restrict__ bias, const float* __restrict__ res,
    float* __restrict__ out, int N, int K)
{
    const int BM = 128, BN = 128, BK = 16;
    __shared__ float As[BM][BK + 1];
    __shared__ float Bs[BK][BN + 1];

    int tid = threadIdx.x;
    int nbx = N / BN;
    int bx = blockIdx.x % nbx;
    int by = blockIdx.x / nbx;
    int row0 = by * BM, col0 = bx * BN;
    int ty = tid >> 4;   // 0..15
    int tx = tid & 15;   // 0..15

    float acc[8][8];
    #pragma unroll
    for (int i = 0; i < 8; i++)
        #pragma unroll
        for (int j = 0; j < 8; j++) acc[i][j] = 0.f;

    for (int k0 = 0; k0 < K; k0 += BK) {
        // A tile: 128x16, each thread 8 consecutive elems of one row
        {
            int r = tid >> 1, cb = (tid & 1) * 8;
            const float* ap = A + (size_t)(row0 + r) * K + k0 + cb;
            #pragma unroll
            for (int i = 0; i < 8; i++) As[r][cb + i] = ap[i];
        }
        // B tile: 16x128
        {
            int r = tid >> 4, cb = (tid & 15) * 8;
            const float* bp = Bw + (size_t)(k0 + r) * N + col0 + cb;
            #pragma unroll
            for (int i = 0; i < 8; i++) Bs[r][cb + i] = bp[i];
        }
        __syncthreads();
        #pragma unroll
        for (int kk = 0; kk < BK; kk++) {
            float a[8], bb[8];
            #pragma unroll
            for (int i = 0; i < 8; i++) a[i] = As[ty * 8 + i][kk];
            #pragma unroll
            for (int j = 0; j < 8; j++) bb[j] = Bs[kk][tx * 8 + j];
            #pragma unroll
            for (int i = 0; i < 8; i++)
                #pragma unroll
                for (int j = 0; j < 8; j++) acc[i][j] += a[i] * bb[j];
        }
        __syncthreads();
    }

    #pragma unroll
    for (int i = 0; i < 8; i++) {
        int r = row0 + ty * 8 + i;
        #pragma unroll
        for (int j = 0; j < 8; j++) {
            int c = col0 + tx * 8 + j;
            float v = acc[i][j];
            if (BIAS) v += bias[c];
            if (RELU) v = fmaxf(v, 0.f);
            if (RES == 1) v += res[(size_t)r * N + c];
            if (OUTMODE == 0) {
                out[(size_t)r * N + c] = v;
            } else {
                int b = r >> 12, s = r & (S_ - 1);
                int h = c >> 6, kk2 = c & 63;
                out[((size_t)(b * H_ + h) * S_ + s) * 64 + kk2] = v;
            }
        }
    }
}

// ---------------------------------------------------------------------------
// LSH hash: bucket = argmax over concat([r, -r]), r = t . rot[h]
// t: [BH, S, 64] f32 ; rot: [H,64,32] f32 ; bucket: [BH,S] int
// argmax tie-break = first index (strict > scans), matching jnp.argmax.
// ---------------------------------------------------------------------------
__global__ __launch_bounds__(256) void hash_k(
    const float* __restrict__ t, const float* __restrict__ rot,
    int* __restrict__ bucket)
{
    int bh = blockIdx.x >> 4;
    int st = blockIdx.x & 15;
    int h = bh % H_;
    __shared__ float rs[64][32];
    int tid = threadIdx.x;
    for (int e = tid; e < 2048; e += 256)
        rs[e >> 5][e & 31] = rot[h * 2048 + e];
    __syncthreads();

    int s = st * 256 + tid;
    const float* qr = t + ((size_t)bh * S_ + s) * 64;
    float qv[64];
    #pragma unroll
    for (int i = 0; i < 64; i++) qv[i] = qr[i];
    float r[32];
    #pragma unroll
    for (int j = 0; j < 32; j++) {
        float a = 0.f;
        #pragma unroll
        for (int kk = 0; kk < 64; kk++) a += qv[kk] * rs[kk][j];
        r[j] = a;
    }
    float best = -INFINITY; int bi = 0;
    #pragma unroll
    for (int j = 0; j < 32; j++) { if (r[j] > best) { best = r[j]; bi = j; } }
    #pragma unroll
    for (int j = 0; j < 32; j++) { float v = -r[j]; if (v > best) { best = v; bi = 32 + j; } }
    bucket[(size_t)bh * S_ + s] = bi;
}

// ---------------------------------------------------------------------------
// Stable counting sort by bucket per (b,h). 1 wave per (b,h); thread t owns
// bucket value t; sequential scan keeps position order (stability) — exactly
// argsort(bucket*S + pos).
// ---------------------------------------------------------------------------
__global__ __launch_bounds__(64) void sort_k(
    const int* __restrict__ bucket, int* __restrict__ perm)
{
    int bh = blockIdx.x;
    __shared__ int lb[S_];
    int tid = threadIdx.x;
    for (int i = tid; i < S_; i += 64) lb[i] = bucket[(size_t)bh * S_ + i];
    __syncthreads();
    int cnt = 0;
    for (int i = 0; i < S_; i++) cnt += (lb[i] == tid) ? 1 : 0;
    int incl = cnt;
    #pragma unroll
    for (int off = 1; off < 64; off <<= 1) {
        int n = __shfl_up(incl, off, 64);
        if (tid >= off) incl += n;
    }
    int idx = incl - cnt;
    int* pr = perm + (size_t)bh * S_;
    for (int i = 0; i < S_; i++)
        if (lb[i] == tid) pr[idx++] = i;
}

// ---------------------------------------------------------------------------
// Chunked LSH attention. 1 wave per (b,h,chunk); thread i = query row i.
// kv window = [chunk (c-1) mod NC, chunk c]  (= reference's roll+concat).
// Two-pass softmax with -1e9 mask reproduces the uniform fallback exactly.
// Output scattered to unsorted position: o[(b*S + s_orig)*512 + h*64 + d].
// LDS = 64 KiB exactly (k,v f32); key buckets live in registers via shfl.
// ---------------------------------------------------------------------------
__global__ __launch_bounds__(64) void attn_k(
    const float* __restrict__ q, const float* __restrict__ k,
    const float* __restrict__ v, const int* __restrict__ bq,
    const int* __restrict__ bk, const int* __restrict__ permq,
    const int* __restrict__ permk, float* __restrict__ o)
{
    int bid = blockIdx.x;
    int c = bid % NC_;
    int bh = bid / NC_;
    int b = bh / H_, h = bh % H_;
    __shared__ float kx[128][64];
    __shared__ float vx[128][64];
    int tid = threadIdx.x;
    const size_t bhS = (size_t)bh * S_;

    // stage 128 k/v rows; lane L handles column d=L of each row:
    // coalesced global reads, conflict-free LDS writes (bank = L&31).
    int bk_reg[2];
    #pragma unroll
    for (int rep = 0; rep < 2; rep++) {
        int j = rep * 64 + tid;
        int sidx = (j < 64) ? (((c + NC_ - 1) % NC_) * 64 + j)
                            : (c * 64 + (j - 64));
        bk_reg[rep] = bk[bhS + permk[bhS + sidx]];
    }
    for (int r = 0; r < 128; r++) {
        int sidx = (r < 64) ? (((c + NC_ - 1) % NC_) * 64 + r)
                            : (c * 64 + (r - 64));
        int sk = permk[bhS + sidx];
        kx[r][tid] = k[(bhS + sk) * 64 + tid];
        vx[r][tid] = v[(bhS + sk) * 64 + tid];
    }
    __syncthreads();

    int sq = permq[bhS + c * 64 + tid];
    const float* qr = q + (bhS + sq) * 64;
    float qi[64];
    #pragma unroll
    for (int d = 0; d < 64; d++) qi[d] = qr[d];
    int bqi = bq[bhS + sq];

    // 128-bit per-thread match mask
    unsigned long long m_lo = 0ull, m_hi = 0ull;
    for (int j = 0; j < 64; j++) {
        if (bqi == __shfl(bk_reg[0], j, 64)) m_lo |= (1ull << j);
        if (bqi == __shfl(bk_reg[1], j, 64)) m_hi |= (1ull << j);
    }

    float m = -INFINITY, l = 0.f;
    for (int j = 0; j < 128; j++) {
        float s = 0.f;
        #pragma unroll
        for (int d = 0; d < 64; d++) s += qi[d] * kx[j][d];
        bool match = (j < 64) ? ((m_lo >> j) & 1ull) : ((m_hi >> (j - 64)) & 1ull);
        float sc = match ? s * 0.125f : -1e9f;
        float mn = fmaxf(m, sc);
        l = l * expf(m - mn) + expf(sc - mn);
        m = mn;
    }

    float acc[64];
    #pragma unroll
    for (int d = 0; d < 64; d++) acc[d] = 0.f;
    for (int j = 0; j < 128; j++) {
        float s = 0.f;
        #pragma unroll
        for (int d = 0; d < 64; d++) s += qi[d] * kx[j][d];
        bool match = (j < 64) ? ((m_lo >> j) & 1ull) : ((m_hi >> (j - 64)) & 1ull);
        float sc = match ? s * 0.125f : -1e9f;
        float p = expf(sc - m);
        #pragma unroll
        for (int d = 0; d < 64; d++) acc[d] += p * vx[j][d];
    }
    float inv = 1.0f / l;
    float* orow = o + ((size_t)b * S_ + sq) * 512 + h * 64;
    #pragma unroll
    for (int d = 0; d < 64; d++) orow[d] = acc[d] * inv;
}

// ---------------------------------------------------------------------------
// LayerNorm per row of [M, 512]. In-place safe (row-owned by block).
// ---------------------------------------------------------------------------
__global__ __launch_bounds__(256) void ln_k(
    const float* __restrict__ x, const float* __restrict__ g,
    const float* __restrict__ bvec, float* __restrict__ out)
{
    int row = blockIdx.x;
    int tid = threadIdx.x;
    __shared__ float red[256];
    const float* xr = x + (size_t)row * D_;
    float v0 = xr[tid], v1 = xr[tid + 256];
    red[tid] = v0 + v1;
    __syncthreads();
    for (int off = 128; off > 0; off >>= 1) {
        if (tid < off) red[tid] += red[tid + off];
        __syncthreads();
    }
    float mean = red[0] / 512.f;
    __syncthreads();
    float d0 = v0 - mean, d1 = v1 - mean;
    red[tid] = d0 * d0 + d1 * d1;
    __syncthreads();
    for (int off = 128; off > 0; off >>= 1) {
        if (tid < off) red[tid] += red[tid + off];
        __syncthreads();
    }
    float var = red[0] / 512.f;
    float rs = 1.0f / sqrtf(var + 1e-5f);
    out[(size_t)row * D_ + tid] = d0 * rs * g[tid] + bvec[tid];
    out[(size_t)row * D_ + tid + 256] = d1 * rs * g[tid + 256] + bvec[tid + 256];
}

// ---------------------------------------------------------------------------
extern "C" void kernel_launch(void* const* d_in, const int* in_sizes, int n_in,
                              void* d_out, int out_size, void* d_ws, size_t ws_size,
                              hipStream_t stream)
{
    (void)in_sizes; (void)n_in; (void)out_size; (void)ws_size;
    const float* dec   = (const float*)d_in[0];
    const float* enc   = (const float*)d_in[1];
    const float* sa_Wq = (const float*)d_in[2];
    const float* sa_Wk = (const float*)d_in[3];
    const float* sa_Wv = (const float*)d_in[4];
    const float* sa_Wo = (const float*)d_in[5];
    const float* sa_g  = (const float*)d_in[6];
    const float* sa_b  = (const float*)d_in[7];
    const float* sa_rot= (const float*)d_in[8];
    const float* ca_Wq = (const float*)d_in[9];
    const float* ca_Wk = (const float*)d_in[10];
    const float* ca_Wv = (const float*)d_in[11];
    const float* ca_Wo = (const float*)d_in[12];
    const float* ca_g  = (const float*)d_in[13];
    const float* ca_b  = (const float*)d_in[14];
    const float* ca_rot= (const float*)d_in[15];
    const float* ff_W1 = (const float*)d_in[16];
    const float* ff_b1 = (const float*)d_in[17];
    const float* ff_W2 = (const float*)d_in[18];
    const float* ff_b2 = (const float*)d_in[19];
    const float* ff_g  = (const float*)d_in[20];
    const float* ff_b  = (const float*)d_in[21];

    char* ws = (char*)d_ws;
    float* qb   = (float*)(ws + 0);
    float* kb   = (float*)(ws + 33554432);
    float* vb   = (float*)(ws + 67108864);
    float* ob   = (float*)(ws + 100663296);
    float* act0 = (float*)(ws + 134217728);
    float* act1 = (float*)(ws + 167772160);
    int* bqb = (int*)(ws + 201326592);
    int* bkb = (int*)(ws + 201850880);
    int* pqb = (int*)(ws + 202375168);
    int* pkb = (int*)(ws + 202899456);
    float* hid = (float*)(ws + 0);   // overlays qb..ob (134.2MB) during FF

    dim3 blk(256);
    const int g512 = (M_ / 128) * (512 / 128);    // 512 blocks
    const int g2048 = (M_ / 128) * (2048 / 128);  // 2048 blocks

    // ---------------- self-attention ----------------
    gemm_k<1,0,false,false><<<g512, blk, 0, stream>>>(dec, sa_Wq, nullptr, nullptr, qb, 512, 512);
    gemm_k<1,0,false,false><<<g512, blk, 0, stream>>>(dec, sa_Wk, nullptr, nullptr, kb, 512, 512);
    gemm_k<1,0,false,false><<<g512, blk, 0, stream>>>(dec, sa_Wv, nullptr, nullptr, vb, 512, 512);
    hash_k<<<BH_ * 16, blk, 0, stream>>>(qb, sa_rot, bqb);
    hash_k<<<BH_ * 16, blk, 0, stream>>>(kb, sa_rot, bkb);
    sort_k<<<BH_, dim3(64), 0, stream>>>(bqb, pqb);
    sort_k<<<BH_, dim3(64), 0, stream>>>(bkb, pkb);
    attn_k<<<BH_ * NC_, dim3(64), 0, stream>>>(qb, kb, vb, bqb, bkb, pqb, pkb, ob);
    gemm_k<0,1,false,false><<<g512, blk, 0, stream>>>(ob, sa_Wo, nullptr, dec, act0, 512, 512);
    ln_k<<<M_, blk, 0, stream>>>(act0, sa_g, sa_b, act0);

    // ---------------- cross-attention ----------------
    gemm_k<1,0,false,false><<<g512, blk, 0, stream>>>(act0, ca_Wq, nullptr, nullptr, qb, 512, 512);
    gemm_k<1,0,false,false><<<g512, blk, 0, stream>>>(enc, ca_Wk, nullptr, nullptr, kb, 512, 512);
    gemm_k<1,0,false,false><<<g512, blk, 0, stream>>>(enc, ca_Wv, nullptr, nullptr, vb, 512, 512);
    hash_k<<<BH_ * 16, blk, 0, stream>>>(qb, ca_rot, bqb);
    hash_k<<<BH_ * 16, blk, 0, stream>>>(kb, ca_rot, bkb);
    sort_k<<<BH_, dim3(64), 0, stream>>>(bqb, pqb);
    sort_k<<<BH_, dim3(64), 0, stream>>>(bkb, pkb);
    attn_k<<<BH_ * NC_, dim3(64), 0, stream>>>(qb, kb, vb, bqb, bkb, pqb, pkb, ob);
    gemm_k<0,1,false,false><<<g512, blk, 0, stream>>>(ob, ca_Wo, nullptr, act0, act1, 512, 512);
    ln_k<<<M_, blk, 0, stream>>>(act1, ca_g, ca_b, act1);

    // ---------------- feed-forward ----------------
    gemm_k<0,0,true,true><<<g2048, blk, 0, stream>>>(act1, ff_W1, ff_b1, nullptr, hid, 2048, 512);
    gemm_k<0,1,true,false><<<g512, blk, 0, stream>>>(hid, ff_W2, ff_b2, act1, act0, 512, 2048);
    ln_k<<<M_, blk, 0, stream>>>(act0, ff_g, ff_b, (float*)d_out);
}

// Round 3
// 3424.961 us; speedup vs baseline: 1.3030x; 1.3030x over previous
//
#include <hip/hip_runtime.h>
#include <hip/hip_bf16.h>
#include <math.h>

typedef __hip_bfloat16 bf16;

#define B_ 4
#define S_ 4096
#define D_ 512
#define H_ 8
#define NC_ 64
#define M_ (B_*S_)     // 16384
#define BH_ (B_*H_)    // 32

typedef __attribute__((ext_vector_type(8))) short bfrag;   // 8 bf16 (4 VGPRs)
typedef __attribute__((ext_vector_type(4))) float facc;    // 4 f32 acc

static __device__ __forceinline__ float tof(float x){ return x; }
static __device__ __forceinline__ float tof(bf16 x){ return __bfloat162float(x); }

#define GLL(gp, lp) __builtin_amdgcn_global_load_lds( \
    (const __attribute__((address_space(1))) void*)(gp), \
    (__attribute__((address_space(3))) void*)(lp), 16, 0, 0)

// ---------------------------------------------------------------------------
// f32 VALU GEMM (hash-feeding SA path; f32-class accuracy required).
// OUTMODE: 0 = f32 row-major [M,N], 1 = f32 qkv-scatter [B,H,S,64]
// RES:     0 = none, 1 = f32 residual row-major [M,N]
// Col mapping interleaved (tx + j*16): conflict-free Bs reads.
// ---------------------------------------------------------------------------
template<int OUTMODE, int RES>
__global__ __launch_bounds__(256) void gemm_k(
    const float* __restrict__ A, const float* __restrict__ Bw,
    const float* __restrict__ res, float* __restrict__ out, int N, int K)
{
    const int BM = 128, BN = 128, BK = 16;
    __shared__ float As[BM][BK + 1];
    __shared__ float Bs[BK][BN + 1];

    int tid = threadIdx.x;
    int nbx = N / BN;
    int bx = blockIdx.x % nbx;
    int by = blockIdx.x / nbx;
    int row0 = by * BM, col0 = bx * BN;
    int ty = tid >> 4;   // 0..15
    int tx = tid & 15;   // 0..15

    float acc[8][8];
    #pragma unroll
    for (int i = 0; i < 8; i++)
        #pragma unroll
        for (int j = 0; j < 8; j++) acc[i][j] = 0.f;

    for (int k0 = 0; k0 < K; k0 += BK) {
        {
            int r = tid >> 1, cb = (tid & 1) * 8;
            const float* ap = A + (size_t)(row0 + r) * K + k0 + cb;
            #pragma unroll
            for (int i = 0; i < 8; i++) As[r][cb + i] = ap[i];
        }
        {
            int r = tid >> 4, cb = (tid & 15) * 8;
            const float* bp = Bw + (size_t)(k0 + r) * N + col0 + cb;
            #pragma unroll
            for (int i = 0; i < 8; i++) Bs[r][cb + i] = bp[i];
        }
        __syncthreads();
        #pragma unroll
        for (int kk = 0; kk < BK; kk++) {
            float a[8], bb[8];
            #pragma unroll
            for (int i = 0; i < 8; i++) a[i] = As[ty * 8 + i][kk];
            #pragma unroll
            for (int j = 0; j < 8; j++) bb[j] = Bs[kk][tx + j * 16];
            #pragma unroll
            for (int i = 0; i < 8; i++)
                #pragma unroll
                for (int j = 0; j < 8; j++) acc[i][j] += a[i] * bb[j];
        }
        __syncthreads();
    }

    #pragma unroll
    for (int i = 0; i < 8; i++) {
        int r = row0 + ty * 8 + i;
        #pragma unroll
        for (int j = 0; j < 8; j++) {
            int c = col0 + tx + j * 16;
            float v = acc[i][j];
            if (RES == 1) v += res[(size_t)r * N + c];
            if (OUTMODE == 0) {
                out[(size_t)r * N + c] = v;
            } else {
                int b = r >> 12, s = r & (S_ - 1);
                int h = c >> 6, kk2 = c & 63;
                out[((size_t)(b * H_ + h) * S_ + s) * 64 + kk2] = v;
            }
        }
    }
}

// ---------------------------------------------------------------------------
// bf16 MFMA GEMM (post-hash smooth path). A: [M,K] bf16 RM. Bt: [N,K] bf16.
// 128x128 tile, BK=32, 4 waves (2x2 of 64x64), mfma_f32_16x16x32_bf16.
// OUTMODE: 0 = f32 RM, 1 = bf16 RM, 2 = bf16 scatter [B,H,S,64]
// RES: 0/1 (f32 RM). BIAS: f32 [N]. RELU.
// ---------------------------------------------------------------------------
template<int OUTMODE, int RES, bool BIAS, bool RELU>
__global__ __launch_bounds__(256) void mgemm_k(
    const short* __restrict__ A, const short* __restrict__ Bt,
    const float* __restrict__ bias, const float* __restrict__ res,
    void* __restrict__ out, int N, int K)
{
    __shared__ short As[128 * 32];
    __shared__ short Bs[128 * 32];

    int tid = threadIdx.x;
    int wave = tid >> 6, lane = tid & 63;
    int nbx = N >> 7;
    int bx = blockIdx.x % nbx, by = blockIdx.x / nbx;
    int row0 = by << 7, col0 = bx << 7;
    int wr = wave >> 1, wc = wave & 1;   // 64x64 wave tile
    int fr = lane & 15, fq = lane >> 4;

    facc acc[4][4];
    facc zero = {0.f, 0.f, 0.f, 0.f};
    #pragma unroll
    for (int m = 0; m < 4; m++)
        #pragma unroll
        for (int n = 0; n < 4; n++) acc[m][n] = zero;

    // per-lane global source: row = wave*32 + lane/4 (+16 for 2nd inst),
    // 16B chunk = (lane&3)*8 elems. LDS dest = wave-uniform base + lane*16B.
    const short* gA = A + (size_t)(row0 + (wave << 5) + (lane >> 2)) * K + ((lane & 3) << 3);
    const short* gB = Bt + (size_t)(col0 + (wave << 5) + (lane >> 2)) * K + ((lane & 3) << 3);

    for (int k0 = 0; k0 < K; k0 += 32) {
        GLL(gA + k0,                 &As[wave << 10]);
        GLL(gA + k0 + (size_t)16 * K, &As[(wave << 10) + 512]);
        GLL(gB + k0,                 &Bs[wave << 10]);
        GLL(gB + k0 + (size_t)16 * K, &Bs[(wave << 10) + 512]);
        __syncthreads();

        bfrag av[4], bv[4];
        #pragma unroll
        for (int m = 0; m < 4; m++)
            av[m] = *reinterpret_cast<const bfrag*>(&As[(((wr << 6) + (m << 4) + fr) << 5) + (fq << 3)]);
        #pragma unroll
        for (int n = 0; n < 4; n++)
            bv[n] = *reinterpret_cast<const bfrag*>(&Bs[(((wc << 6) + (n << 4) + fr) << 5) + (fq << 3)]);
        #pragma unroll
        for (int m = 0; m < 4; m++)
            #pragma unroll
            for (int n = 0; n < 4; n++)
                acc[m][n] = __builtin_amdgcn_mfma_f32_16x16x32_bf16(av[m], bv[n], acc[m][n], 0, 0, 0);
        __syncthreads();
    }

    #pragma unroll
    for (int m = 0; m < 4; m++) {
        #pragma unroll
        for (int n = 0; n < 4; n++) {
            #pragma unroll
            for (int r = 0; r < 4; r++) {
                int row = row0 + (wr << 6) + (m << 4) + (fq << 2) + r;
                int col = col0 + (wc << 6) + (n << 4) + fr;
                float v = acc[m][n][r];
                if (BIAS) v += bias[col];
                if (RELU) v = fmaxf(v, 0.f);
                if (RES == 1) v += res[(size_t)row * N + col];
                if (OUTMODE == 0) {
                    ((float*)out)[(size_t)row * N + col] = v;
                } else if (OUTMODE == 1) {
                    ((bf16*)out)[(size_t)row * N + col] = __float2bfloat16(v);
                } else {
                    int b = row >> 12, s = row & (S_ - 1);
                    int h = col >> 6, kk2 = col & 63;
                    ((bf16*)out)[(((size_t)(b * H_ + h) * S_ + s) << 6) + kk2] = __float2bfloat16(v);
                }
            }
        }
    }
}

// ---------------------------------------------------------------------------
// Weight converters
// ---------------------------------------------------------------------------
// Wt[n][k] = bf16(W[k][n])
__global__ __launch_bounds__(256) void convw_k(
    const float* __restrict__ W, bf16* __restrict__ Wt, int N, int K)
{
    int i = blockIdx.x * 256 + threadIdx.x;
    int n = i / K, k = i % K;
    Wt[i] = __float2bfloat16(W[(size_t)k * N + n]);
}

// wrot[d][h*32+j] = sum_k W[d][h][k] * rot[h][k][j]   (f32 exact-class)
__global__ __launch_bounds__(256) void wrot_k(
    const float* __restrict__ W, const float* __restrict__ rot,
    float* __restrict__ wrot)
{
    int d = blockIdx.x, t = threadIdx.x;
    int h = t >> 5, j = t & 31;
    float a = 0.f;
    #pragma unroll
    for (int k = 0; k < 64; k++)
        a += W[(size_t)(d * H_ + h) * 64 + k] * rot[(size_t)(h * 64 + k) * 32 + j];
    wrot[(size_t)d * 256 + t] = a;
}

// f32 -> bf16 flat cast (4 elems/thread)
__global__ __launch_bounds__(256) void cast_k(
    const float* __restrict__ x, bf16* __restrict__ y)
{
    size_t i = ((size_t)blockIdx.x * 256 + threadIdx.x) * 4;
    float4 v = *reinterpret_cast<const float4*>(x + i);
    y[i]     = __float2bfloat16(v.x);
    y[i + 1] = __float2bfloat16(v.y);
    y[i + 2] = __float2bfloat16(v.z);
    y[i + 3] = __float2bfloat16(v.w);
}

// ---------------------------------------------------------------------------
// SA hash (from f32 q/k scatter): bucket = argmax concat([r,-r]), r = t.rot
// ---------------------------------------------------------------------------
__global__ __launch_bounds__(256) void hash_k(
    const float* __restrict__ t, const float* __restrict__ rot,
    int* __restrict__ bucket)
{
    int bh = blockIdx.x >> 4;
    int st = blockIdx.x & 15;
    int h = bh % H_;
    __shared__ float rs[64][32];
    int tid = threadIdx.x;
    for (int e = tid; e < 2048; e += 256)
        rs[e >> 5][e & 31] = rot[h * 2048 + e];
    __syncthreads();

    int s = st * 256 + tid;
    const float* qr = t + ((size_t)bh * S_ + s) * 64;
    float qv[64];
    #pragma unroll
    for (int i = 0; i < 64; i++) qv[i] = qr[i];
    float r[32];
    #pragma unroll
    for (int j = 0; j < 32; j++) {
        float a = 0.f;
        #pragma unroll
        for (int kk = 0; kk < 64; kk++) a += qv[kk] * rs[kk][j];
        r[j] = a;
    }
    float best = -INFINITY; int bi = 0;
    #pragma unroll
    for (int j = 0; j < 32; j++) { if (r[j] > best) { best = r[j]; bi = j; } }
    #pragma unroll
    for (int j = 0; j < 32; j++) { float v = -r[j]; if (v > best) { best = v; bi = 32 + j; } }
    bucket[(size_t)bh * S_ + s] = bi;
}

// ---------------------------------------------------------------------------
// CA hash fused: r[b,s,h,j] = x[b,s,:] . wrot[:, h*32+j], argmax over 64.
// One block per row; thread t = (h = t>>5, j = t&31). First-index tie-break.
// ---------------------------------------------------------------------------
__global__ __launch_bounds__(256) void rhash_k(
    const float* __restrict__ x, const float* __restrict__ wrot,
    int* __restrict__ bucket)
{
    __shared__ float xs[512];
    int tid = threadIdx.x;
    const float* xr = x + (size_t)blockIdx.x * 512;
    xs[tid] = xr[tid];
    xs[tid + 256] = xr[tid + 256];
    __syncthreads();
    float a = 0.f;
    #pragma unroll 8
    for (int d = 0; d < 512; d++) a += xs[d] * wrot[(size_t)d * 256 + tid];

    int j = tid & 31;
    float bv_ = a; int bi = j;
    float nb = -a;
    if (nb > bv_) { bv_ = nb; bi = 32 + j; }
    #pragma unroll
    for (int off = 1; off < 32; off <<= 1) {
        float ov = __shfl_xor(bv_, off, 64);
        int oi = __shfl_xor(bi, off, 64);
        if (ov > bv_ || (ov == bv_ && oi < bi)) { bv_ = ov; bi = oi; }
    }
    if (j == 0) {
        int b = blockIdx.x >> 12, s = blockIdx.x & (S_ - 1), h = tid >> 5;
        bucket[((size_t)(b * H_ + h)) * S_ + s] = bi;
    }
}

// ---------------------------------------------------------------------------
// Stable counting sort by bucket per (b,h) — argsort(bucket*S + pos).
// ---------------------------------------------------------------------------
__global__ __launch_bounds__(64) void sort_k(
    const int* __restrict__ bucket, int* __restrict__ perm)
{
    int bh = blockIdx.x;
    __shared__ int lb[S_];
    int tid = threadIdx.x;
    for (int i = tid; i < S_; i += 64) lb[i] = bucket[(size_t)bh * S_ + i];
    __syncthreads();
    int cnt = 0;
    for (int i = 0; i < S_; i++) cnt += (lb[i] == tid) ? 1 : 0;
    int incl = cnt;
    #pragma unroll
    for (int off = 1; off < 64; off <<= 1) {
        int n = __shfl_up(incl, off, 64);
        if (tid >= off) incl += n;
    }
    int idx = incl - cnt;
    int* pr = perm + (size_t)bh * S_;
    for (int i = 0; i < S_; i++)
        if (lb[i] == tid) pr[idx++] = i;
}

// ---------------------------------------------------------------------------
// Chunked LSH attention (templated element type). 1 wave per (b,h,chunk).
// T = float (SA, f32-class) or bf16 (CA, post-hash). Scores/softmax f32.
// ---------------------------------------------------------------------------
template<typename T, typename OT>
__global__ __launch_bounds__(64) void attn_k(
    const T* __restrict__ q, const T* __restrict__ k,
    const T* __restrict__ v, const int* __restrict__ bq,
    const int* __restrict__ bk, const int* __restrict__ permq,
    const int* __restrict__ permk, OT* __restrict__ o)
{
    int bid = blockIdx.x;
    int c = bid % NC_;
    int bh = bid / NC_;
    int b = bh / H_, h = bh % H_;
    __shared__ T kx[128][64];
    __shared__ T vx[128][64];
    int tid = threadIdx.x;
    const size_t bhS = (size_t)bh * S_;

    int bk_reg[2];
    #pragma unroll
    for (int rep = 0; rep < 2; rep++) {
        int jj = rep * 64 + tid;
        int sidx = (jj < 64) ? (((c + NC_ - 1) % NC_) * 64 + jj)
                             : (c * 64 + (jj - 64));
        bk_reg[rep] = bk[bhS + permk[bhS + sidx]];
    }
    for (int r = 0; r < 128; r++) {
        int sidx = (r < 64) ? (((c + NC_ - 1) % NC_) * 64 + r)
                            : (c * 64 + (r - 64));
        int sk = permk[bhS + sidx];
        kx[r][tid] = k[(bhS + sk) * 64 + tid];
        vx[r][tid] = v[(bhS + sk) * 64 + tid];
    }
    __syncthreads();

    int sq = permq[bhS + c * 64 + tid];
    const T* qr = q + (bhS + sq) * 64;
    float qi[64];
    #pragma unroll
    for (int d = 0; d < 64; d++) qi[d] = tof(qr[d]);
    int bqi = bq[bhS + sq];

    unsigned long long m_lo = 0ull, m_hi = 0ull;
    for (int jj = 0; jj < 64; jj++) {
        if (bqi == __shfl(bk_reg[0], jj, 64)) m_lo |= (1ull << jj);
        if (bqi == __shfl(bk_reg[1], jj, 64)) m_hi |= (1ull << jj);
    }

    float m = -INFINITY, l = 0.f;
    for (int jj = 0; jj < 128; jj++) {
        float s = 0.f;
        #pragma unroll
        for (int d = 0; d < 64; d++) s += qi[d] * tof(kx[jj][d]);
        bool match = (jj < 64) ? ((m_lo >> jj) & 1ull) : ((m_hi >> (jj - 64)) & 1ull);
        float sc = match ? s * 0.125f : -1e9f;
        float mn = fmaxf(m, sc);
        l = l * expf(m - mn) + expf(sc - mn);
        m = mn;
    }

    float acc[64];
    #pragma unroll
    for (int d = 0; d < 64; d++) acc[d] = 0.f;
    for (int jj = 0; jj < 128; jj++) {
        float s = 0.f;
        #pragma unroll
        for (int d = 0; d < 64; d++) s += qi[d] * tof(kx[jj][d]);
        bool match = (jj < 64) ? ((m_lo >> jj) & 1ull) : ((m_hi >> (jj - 64)) & 1ull);
        float sc = match ? s * 0.125f : -1e9f;
        float p = expf(sc - m);
        #pragma unroll
        for (int d = 0; d < 64; d++) acc[d] += p * tof(vx[jj][d]);
    }
    float inv = 1.0f / l;
    OT* orow = o + ((size_t)b * S_ + sq) * 512 + h * 64;
    #pragma unroll
    for (int d = 0; d < 64; d++) {
        float ov = acc[d] * inv;
        if (sizeof(OT) == 2) orow[d] = (OT)__float2bfloat16(ov);
        else orow[d] = (OT)ov;
    }
}

// ---------------------------------------------------------------------------
// LayerNorm per row of [M,512], f32 out (+ optional bf16 copy).
// ---------------------------------------------------------------------------
template<bool BFC>
__global__ __launch_bounds__(256) void ln_k(
    const float* __restrict__ x, const float* __restrict__ g,
    const float* __restrict__ bvec, float* __restrict__ out,
    bf16* __restrict__ bfout)
{
    int row = blockIdx.x;
    int tid = threadIdx.x;
    __shared__ float red[256];
    const float* xr = x + (size_t)row * D_;
    float v0 = xr[tid], v1 = xr[tid + 256];
    red[tid] = v0 + v1;
    __syncthreads();
    for (int off = 128; off > 0; off >>= 1) {
        if (tid < off) red[tid] += red[tid + off];
        __syncthreads();
    }
    float mean = red[0] / 512.f;
    __syncthreads();
    float d0 = v0 - mean, d1 = v1 - mean;
    red[tid] = d0 * d0 + d1 * d1;
    __syncthreads();
    for (int off = 128; off > 0; off >>= 1) {
        if (tid < off) red[tid] += red[tid + off];
        __syncthreads();
    }
    float var = red[0] / 512.f;
    float rs = 1.0f / sqrtf(var + 1e-5f);
    float y0 = d0 * rs * g[tid] + bvec[tid];
    float y1 = d1 * rs * g[tid + 256] + bvec[tid + 256];
    out[(size_t)row * D_ + tid] = y0;
    out[(size_t)row * D_ + tid + 256] = y1;
    if (BFC) {
        bfout[(size_t)row * D_ + tid] = __float2bfloat16(y0);
        bfout[(size_t)row * D_ + tid + 256] = __float2bfloat16(y1);
    }
}

// ---------------------------------------------------------------------------
extern "C" void kernel_launch(void* const* d_in, const int* in_sizes, int n_in,
                              void* d_out, int out_size, void* d_ws, size_t ws_size,
                              hipStream_t stream)
{
    (void)in_sizes; (void)n_in; (void)out_size; (void)ws_size;
    const float* dec   = (const float*)d_in[0];
    const float* enc   = (const float*)d_in[1];
    const float* sa_Wq = (const float*)d_in[2];
    const float* sa_Wk = (const float*)d_in[3];
    const float* sa_Wv = (const float*)d_in[4];
    const float* sa_Wo = (const float*)d_in[5];
    const float* sa_g  = (const float*)d_in[6];
    const float* sa_b  = (const float*)d_in[7];
    const float* sa_rot= (const float*)d_in[8];
    const float* ca_Wq = (const float*)d_in[9];
    const float* ca_Wk = (const float*)d_in[10];
    const float* ca_Wv = (const float*)d_in[11];
    const float* ca_Wo = (const float*)d_in[12];
    const float* ca_g  = (const float*)d_in[13];
    const float* ca_b  = (const float*)d_in[14];
    const float* ca_rot= (const float*)d_in[15];
    const float* ff_W1 = (const float*)d_in[16];
    const float* ff_b1 = (const float*)d_in[17];
    const float* ff_W2 = (const float*)d_in[18];
    const float* ff_b2 = (const float*)d_in[19];
    const float* ff_g  = (const float*)d_in[20];
    const float* ff_b  = (const float*)d_in[21];

    char* ws = (char*)d_ws;
    const size_t MB = 1ull << 20;
    // SA phase (f32)
    float* qb     = (float*)(ws + 0);        // 32MB
    float* kb     = (float*)(ws + 32*MB);    // 32MB
    float* vb     = (float*)(ws + 64*MB);    // 32MB
    float* ob     = (float*)(ws + 96*MB);    // 32MB
    float* act0   = (float*)(ws + 128*MB);   // 32MB (live thru ca_Wo residual)
    bf16*  act0bf = (bf16*)(ws + 160*MB);    // 16MB
    // CA phase overlays (qb..ob dead)
    bf16*  cq     = (bf16*)(ws + 0);         // 16MB
    bf16*  ck     = (bf16*)(ws + 16*MB);     // 16MB
    bf16*  cv     = (bf16*)(ws + 32*MB);     // 16MB
    bf16*  caOut  = (bf16*)(ws + 48*MB);     // 16MB
    bf16*  encbf  = (bf16*)(ws + 64*MB);     // 16MB (after SA attn)
    bf16*  act1bf = (bf16*)(ws + 80*MB);     // 16MB
    float* act1   = (float*)(ws + 96*MB);    // 32MB
    // FF overlays (cq..caOut dead)
    bf16*  hid    = (bf16*)(ws + 0);         // 64MB
    float* ffout  = (float*)(ws + 128*MB);   // 32MB (act0 dead)
    // weights / hash
    bf16*  caWqt  = (bf16*)(ws + 176*MB);
    bf16*  caWkt  = (bf16*)(ws + 176*MB + 512*1024);
    bf16*  caWvt  = (bf16*)(ws + 177*MB);
    bf16*  caWot  = (bf16*)(ws + 177*MB + 512*1024);
    bf16*  ffW1t  = (bf16*)(ws + 178*MB);    // 2MB
    bf16*  ffW2t  = (bf16*)(ws + 180*MB);    // 2MB
    float* wrotq  = (float*)(ws + 182*MB);
    float* wrotk  = (float*)(ws + 182*MB + 512*1024);
    int*   bqb    = (int*)(ws + 183*MB);
    int*   bkb    = (int*)(ws + 183*MB + 512*1024);
    int*   pqb    = (int*)(ws + 184*MB);
    int*   pkb    = (int*)(ws + 184*MB + 512*1024);   // ends at 185MB

    dim3 blk(256);
    const int g512  = (M_ / 128) * (512 / 128);    // 512 blocks
    const int g2048 = (M_ / 128) * (2048 / 128);   // 2048 blocks

    // ---- converters (independent) ----
    wrot_k<<<512, blk, 0, stream>>>(ca_Wq, ca_rot, wrotq);
    wrot_k<<<512, blk, 0, stream>>>(ca_Wk, ca_rot, wrotk);
    convw_k<<<1024, blk, 0, stream>>>(ca_Wq, caWqt, 512, 512);
    convw_k<<<1024, blk, 0, stream>>>(ca_Wk, caWkt, 512, 512);
    convw_k<<<1024, blk, 0, stream>>>(ca_Wv, caWvt, 512, 512);
    convw_k<<<1024, blk, 0, stream>>>(ca_Wo, caWot, 512, 512);
    convw_k<<<4096, blk, 0, stream>>>(ff_W1, ffW1t, 2048, 512);
    convw_k<<<4096, blk, 0, stream>>>(ff_W2, ffW2t, 512, 2048);

    // ---------------- self-attention (f32-class, feeds ca-hash) ----------
    gemm_k<1,0><<<g512, blk, 0, stream>>>(dec, sa_Wq, nullptr, qb, 512, 512);
    gemm_k<1,0><<<g512, blk, 0, stream>>>(dec, sa_Wk, nullptr, kb, 512, 512);
    gemm_k<1,0><<<g512, blk, 0, stream>>>(dec, sa_Wv, nullptr, vb, 512, 512);
    hash_k<<<BH_ * 16, blk, 0, stream>>>(qb, sa_rot, bqb);
    hash_k<<<BH_ * 16, blk, 0, stream>>>(kb, sa_rot, bkb);
    sort_k<<<BH_, dim3(64), 0, stream>>>(bqb, pqb);
    sort_k<<<BH_, dim3(64), 0, stream>>>(bkb, pkb);
    attn_k<float,float><<<BH_ * NC_, dim3(64), 0, stream>>>(qb, kb, vb, bqb, bkb, pqb, pkb, ob);
    gemm_k<0,1><<<g512, blk, 0, stream>>>(ob, sa_Wo, dec, act0, 512, 512);
    ln_k<true><<<M_, blk, 0, stream>>>(act0, sa_g, sa_b, act0, act0bf);

    // ---------------- cross-attention ----------------
    cast_k<<<M_ * 512 / 1024, blk, 0, stream>>>(enc, encbf);
    rhash_k<<<M_, blk, 0, stream>>>(act0, wrotq, bqb);
    rhash_k<<<M_, blk, 0, stream>>>(enc,  wrotk, bkb);
    sort_k<<<BH_, dim3(64), 0, stream>>>(bqb, pqb);
    sort_k<<<BH_, dim3(64), 0, stream>>>(bkb, pkb);
    mgemm_k<2,0,false,false><<<g512, blk, 0, stream>>>((const short*)act0bf, (const short*)caWqt, nullptr, nullptr, cq, 512, 512);
    mgemm_k<2,0,false,false><<<g512, blk, 0, stream>>>((const short*)encbf, (const short*)caWkt, nullptr, nullptr, ck, 512, 512);
    mgemm_k<2,0,false,false><<<g512, blk, 0, stream>>>((const short*)encbf, (const short*)caWvt, nullptr, nullptr, cv, 512, 512);
    attn_k<bf16,bf16><<<BH_ * NC_, dim3(64), 0, stream>>>(cq, ck, cv, bqb, bkb, pqb, pkb, caOut);
    mgemm_k<0,1,false,false><<<g512, blk, 0, stream>>>((const short*)caOut, (const short*)caWot, nullptr, act0, act1, 512, 512);
    ln_k<true><<<M_, blk, 0, stream>>>(act1, ca_g, ca_b, act1, act1bf);

    // ---------------- feed-forward ----------------
    mgemm_k<1,0,true,true><<<g2048, blk, 0, stream>>>((const short*)act1bf, (const short*)ffW1t, ff_b1, nullptr, hid, 2048, 512);
    mgemm_k<0,1,true,false><<<g512, blk, 0, stream>>>((const short*)hid, (const short*)ffW2t, ff_b2, act1, ffout, 512, 2048);
    ln_k<false><<<M_, blk, 0, stream>>>(ffout, ff_g, ff_b, (float*)d_out, nullptr);
}

// Round 4
// 3252.374 us; speedup vs baseline: 1.3722x; 1.0531x over previous
//
#include <hip/hip_runtime.h>
#include <hip/hip_bf16.h>
#include <math.h>

typedef __hip_bfloat16 bf16;

#define B_ 4
#define S_ 4096
#define D_ 512
#define H_ 8
#define NC_ 64
#define M_ (B_*S_)     // 16384
#define BH_ (B_*H_)    // 32

typedef __attribute__((ext_vector_type(8))) short bfrag;   // 8 bf16 (4 VGPRs)
typedef __attribute__((ext_vector_type(4))) float facc;    // 4 f32 acc

static __device__ __forceinline__ float tof(float x){ return x; }
static __device__ __forceinline__ float tof(bf16 x){ return __bfloat162float(x); }

#define GLL(gp, lp) __builtin_amdgcn_global_load_lds( \
    (const __attribute__((address_space(1))) void*)(gp), \
    (__attribute__((address_space(3))) void*)(lp), 16, 0, 0)

// ---------------------------------------------------------------------------
// f32 VALU GEMM (hash-feeding SA path; f32-class accuracy required).
// OUTMODE: 0 = f32 row-major [M,N], 1 = f32 qkv-scatter [B,H,S,64]
// RES:     0 = none, 1 = f32 residual row-major [M,N]
// ---------------------------------------------------------------------------
template<int OUTMODE, int RES>
__global__ __launch_bounds__(256) void gemm_k(
    const float* __restrict__ A, const float* __restrict__ Bw,
    const float* __restrict__ res, float* __restrict__ out, int N, int K)
{
    const int BM = 128, BN = 128, BK = 16;
    __shared__ float As[BM][BK + 1];
    __shared__ float Bs[BK][BN + 1];

    int tid = threadIdx.x;
    int nbx = N / BN;
    int bx = blockIdx.x % nbx;
    int by = blockIdx.x / nbx;
    int row0 = by * BM, col0 = bx * BN;
    int ty = tid >> 4;   // 0..15
    int tx = tid & 15;   // 0..15

    float acc[8][8];
    #pragma unroll
    for (int i = 0; i < 8; i++)
        #pragma unroll
        for (int j = 0; j < 8; j++) acc[i][j] = 0.f;

    for (int k0 = 0; k0 < K; k0 += BK) {
        {
            int r = tid >> 1, cb = (tid & 1) * 8;
            const float* ap = A + (size_t)(row0 + r) * K + k0 + cb;
            #pragma unroll
            for (int i = 0; i < 8; i++) As[r][cb + i] = ap[i];
        }
        {
            int r = tid >> 4, cb = (tid & 15) * 8;
            const float* bp = Bw + (size_t)(k0 + r) * N + col0 + cb;
            #pragma unroll
            for (int i = 0; i < 8; i++) Bs[r][cb + i] = bp[i];
        }
        __syncthreads();
        #pragma unroll
        for (int kk = 0; kk < BK; kk++) {
            float a[8], bb[8];
            #pragma unroll
            for (int i = 0; i < 8; i++) a[i] = As[ty * 8 + i][kk];
            #pragma unroll
            for (int j = 0; j < 8; j++) bb[j] = Bs[kk][tx + j * 16];
            #pragma unroll
            for (int i = 0; i < 8; i++)
                #pragma unroll
                for (int j = 0; j < 8; j++) acc[i][j] += a[i] * bb[j];
        }
        __syncthreads();
    }

    #pragma unroll
    for (int i = 0; i < 8; i++) {
        int r = row0 + ty * 8 + i;
        #pragma unroll
        for (int j = 0; j < 8; j++) {
            int c = col0 + tx + j * 16;
            float v = acc[i][j];
            if (RES == 1) v += res[(size_t)r * N + c];
            if (OUTMODE == 0) {
                out[(size_t)r * N + c] = v;
            } else {
                int b = r >> 12, s = r & (S_ - 1);
                int h = c >> 6, kk2 = c & 63;
                out[((size_t)(b * H_ + h) * S_ + s) * 64 + kk2] = v;
            }
        }
    }
}

// ---------------------------------------------------------------------------
// bf16 MFMA GEMM (post-hash smooth path). A: [M,K] bf16 RM. Bt: [N,K] bf16.
// ---------------------------------------------------------------------------
template<int OUTMODE, int RES, bool BIAS, bool RELU>
__global__ __launch_bounds__(256) void mgemm_k(
    const short* __restrict__ A, const short* __restrict__ Bt,
    const float* __restrict__ bias, const float* __restrict__ res,
    void* __restrict__ out, int N, int K)
{
    __shared__ short As[128 * 32];
    __shared__ short Bs[128 * 32];

    int tid = threadIdx.x;
    int wave = tid >> 6, lane = tid & 63;
    int nbx = N >> 7;
    int bx = blockIdx.x % nbx, by = blockIdx.x / nbx;
    int row0 = by << 7, col0 = bx << 7;
    int wr = wave >> 1, wc = wave & 1;   // 64x64 wave tile
    int fr = lane & 15, fq = lane >> 4;

    facc acc[4][4];
    facc zero = {0.f, 0.f, 0.f, 0.f};
    #pragma unroll
    for (int m = 0; m < 4; m++)
        #pragma unroll
        for (int n = 0; n < 4; n++) acc[m][n] = zero;

    const short* gA = A + (size_t)(row0 + (wave << 5) + (lane >> 2)) * K + ((lane & 3) << 3);
    const short* gB = Bt + (size_t)(col0 + (wave << 5) + (lane >> 2)) * K + ((lane & 3) << 3);

    for (int k0 = 0; k0 < K; k0 += 32) {
        GLL(gA + k0,                 &As[wave << 10]);
        GLL(gA + k0 + (size_t)16 * K, &As[(wave << 10) + 512]);
        GLL(gB + k0,                 &Bs[wave << 10]);
        GLL(gB + k0 + (size_t)16 * K, &Bs[(wave << 10) + 512]);
        __syncthreads();

        bfrag av[4], bv[4];
        #pragma unroll
        for (int m = 0; m < 4; m++)
            av[m] = *reinterpret_cast<const bfrag*>(&As[(((wr << 6) + (m << 4) + fr) << 5) + (fq << 3)]);
        #pragma unroll
        for (int n = 0; n < 4; n++)
            bv[n] = *reinterpret_cast<const bfrag*>(&Bs[(((wc << 6) + (n << 4) + fr) << 5) + (fq << 3)]);
        #pragma unroll
        for (int m = 0; m < 4; m++)
            #pragma unroll
            for (int n = 0; n < 4; n++)
                acc[m][n] = __builtin_amdgcn_mfma_f32_16x16x32_bf16(av[m], bv[n], acc[m][n], 0, 0, 0);
        __syncthreads();
    }

    #pragma unroll
    for (int m = 0; m < 4; m++) {
        #pragma unroll
        for (int n = 0; n < 4; n++) {
            #pragma unroll
            for (int r = 0; r < 4; r++) {
                int row = row0 + (wr << 6) + (m << 4) + (fq << 2) + r;
                int col = col0 + (wc << 6) + (n << 4) + fr;
                float v = acc[m][n][r];
                if (BIAS) v += bias[col];
                if (RELU) v = fmaxf(v, 0.f);
                if (RES == 1) v += res[(size_t)row * N + col];
                if (OUTMODE == 0) {
                    ((float*)out)[(size_t)row * N + col] = v;
                } else if (OUTMODE == 1) {
                    ((bf16*)out)[(size_t)row * N + col] = __float2bfloat16(v);
                } else {
                    int b = row >> 12, s = row & (S_ - 1);
                    int h = col >> 6, kk2 = col & 63;
                    ((bf16*)out)[(((size_t)(b * H_ + h) * S_ + s) << 6) + kk2] = __float2bfloat16(v);
                }
            }
        }
    }
}

// ---------------------------------------------------------------------------
// Weight converters
// ---------------------------------------------------------------------------
__global__ __launch_bounds__(256) void convw_k(
    const float* __restrict__ W, bf16* __restrict__ Wt, int N, int K)
{
    int i = blockIdx.x * 256 + threadIdx.x;
    int n = i / K, k = i % K;
    Wt[i] = __float2bfloat16(W[(size_t)k * N + n]);
}

__global__ __launch_bounds__(256) void wrot_k(
    const float* __restrict__ W, const float* __restrict__ rot,
    float* __restrict__ wrot)
{
    int d = blockIdx.x, t = threadIdx.x;
    int h = t >> 5, j = t & 31;
    float a = 0.f;
    #pragma unroll
    for (int k = 0; k < 64; k++)
        a += W[(size_t)(d * H_ + h) * 64 + k] * rot[(size_t)(h * 64 + k) * 32 + j];
    wrot[(size_t)d * 256 + t] = a;
}

__global__ __launch_bounds__(256) void cast_k(
    const float* __restrict__ x, bf16* __restrict__ y)
{
    size_t i = ((size_t)blockIdx.x * 256 + threadIdx.x) * 4;
    float4 v = *reinterpret_cast<const float4*>(x + i);
    y[i]     = __float2bfloat16(v.x);
    y[i + 1] = __float2bfloat16(v.y);
    y[i + 2] = __float2bfloat16(v.z);
    y[i + 3] = __float2bfloat16(v.w);
}

// ---------------------------------------------------------------------------
// SA hash
// ---------------------------------------------------------------------------
__global__ __launch_bounds__(256) void hash_k(
    const float* __restrict__ t, const float* __restrict__ rot,
    int* __restrict__ bucket)
{
    int bh = blockIdx.x >> 4;
    int st = blockIdx.x & 15;
    int h = bh % H_;
    __shared__ float rs[64][32];
    int tid = threadIdx.x;
    for (int e = tid; e < 2048; e += 256)
        rs[e >> 5][e & 31] = rot[h * 2048 + e];
    __syncthreads();

    int s = st * 256 + tid;
    const float* qr = t + ((size_t)bh * S_ + s) * 64;
    float qv[64];
    #pragma unroll
    for (int i = 0; i < 64; i++) qv[i] = qr[i];
    float r[32];
    #pragma unroll
    for (int j = 0; j < 32; j++) {
        float a = 0.f;
        #pragma unroll
        for (int kk = 0; kk < 64; kk++) a += qv[kk] * rs[kk][j];
        r[j] = a;
    }
    float best = -INFINITY; int bi = 0;
    #pragma unroll
    for (int j = 0; j < 32; j++) { if (r[j] > best) { best = r[j]; bi = j; } }
    #pragma unroll
    for (int j = 0; j < 32; j++) { float v = -r[j]; if (v > best) { best = v; bi = 32 + j; } }
    bucket[(size_t)bh * S_ + s] = bi;
}

// ---------------------------------------------------------------------------
// CA hash fused from row-major activations
// ---------------------------------------------------------------------------
__global__ __launch_bounds__(256) void rhash_k(
    const float* __restrict__ x, const float* __restrict__ wrot,
    int* __restrict__ bucket)
{
    __shared__ float xs[512];
    int tid = threadIdx.x;
    const float* xr = x + (size_t)blockIdx.x * 512;
    xs[tid] = xr[tid];
    xs[tid + 256] = xr[tid + 256];
    __syncthreads();
    float a = 0.f;
    #pragma unroll 8
    for (int d = 0; d < 512; d++) a += xs[d] * wrot[(size_t)d * 256 + tid];

    int j = tid & 31;
    float bv_ = a; int bi = j;
    float nb = -a;
    if (nb > bv_) { bv_ = nb; bi = 32 + j; }
    #pragma unroll
    for (int off = 1; off < 32; off <<= 1) {
        float ov = __shfl_xor(bv_, off, 64);
        int oi = __shfl_xor(bi, off, 64);
        if (ov > bv_ || (ov == bv_ && oi < bi)) { bv_ = ov; bi = oi; }
    }
    if (j == 0) {
        int b = blockIdx.x >> 12, s = blockIdx.x & (S_ - 1), h = tid >> 5;
        bucket[((size_t)(b * H_ + h)) * S_ + s] = bi;
    }
}

// ---------------------------------------------------------------------------
// Stable counting sort by bucket per (b,h) — argsort(bucket*S + pos).
// ---------------------------------------------------------------------------
__global__ __launch_bounds__(64) void sort_k(
    const int* __restrict__ bucket, int* __restrict__ perm)
{
    int bh = blockIdx.x;
    __shared__ int lb[S_];
    int tid = threadIdx.x;
    for (int i = tid; i < S_; i += 64) lb[i] = bucket[(size_t)bh * S_ + i];
    __syncthreads();
    int cnt = 0;
    for (int i = 0; i < S_; i++) cnt += (lb[i] == tid) ? 1 : 0;
    int incl = cnt;
    #pragma unroll
    for (int off = 1; off < 64; off <<= 1) {
        int n = __shfl_up(incl, off, 64);
        if (tid >= off) incl += n;
    }
    int idx = incl - cnt;
    int* pr = perm + (size_t)bh * S_;
    for (int i = 0; i < S_; i++)
        if (lb[i] == tid) pr[idx++] = i;
}

// ---------------------------------------------------------------------------
// Chunked LSH attention, restructured (round 4):
//  - single QK^T pass, masked scores stored in LDS (thread-private column)
//  - max via 4 independent partial-max chains (no dependent online chain)
//  - K/V share one LDS buffer (restaged); denominator folded into epilogue
//  - float4 LDS broadcasts + 4 partial dot sums -> issue-bound, not
//    latency-bound.
// Semantics identical to two-pass -1e9-masked softmax (incl. uniform
// fallback for fully-masked rows: m=-1e9 -> all p=1 -> mean over 128).
// ---------------------------------------------------------------------------
template<typename T, typename OT>
__global__ __launch_bounds__(64) void attn_k(
    const T* __restrict__ q, const T* __restrict__ k,
    const T* __restrict__ v, const int* __restrict__ bq,
    const int* __restrict__ bk, const int* __restrict__ permq,
    const int* __restrict__ permk, OT* __restrict__ o)
{
    int bid = blockIdx.x;
    int c = bid % NC_;
    int bh = bid / NC_;
    int b = bh / H_, h = bh % H_;
    __shared__ float kv[128][64];   // K, then restaged as V
    __shared__ float sx[128][64];   // masked scores, column tid private
    int tid = threadIdx.x;
    const size_t bhS = (size_t)bh * S_;

    // gather indices + key buckets (held in registers, broadcast via shfl)
    int sk_reg[2], bk_reg[2];
    #pragma unroll
    for (int rep = 0; rep < 2; rep++) {
        int jj = rep * 64 + tid;
        int sidx = (jj < 64) ? (((c + NC_ - 1) % NC_) * 64 + jj)
                             : (c * 64 + (jj - 64));
        int sk = permk[bhS + sidx];
        sk_reg[rep] = sk;
        bk_reg[rep] = bk[bhS + sk];
    }
    // stage K (lane = column d): coalesced reads, conflict-free writes
    for (int r = 0; r < 128; r++) {
        int sk = __shfl(sk_reg[r >> 6], r & 63, 64);
        kv[r][tid] = tof(k[(bhS + sk) * 64 + tid]);
    }
    __syncthreads();

    int sq = permq[bhS + c * 64 + tid];
    const T* qr = q + (bhS + sq) * 64;
    float4 qi[16];
    #pragma unroll
    for (int d4 = 0; d4 < 16; d4++) {
        qi[d4].x = tof(qr[d4 * 4 + 0]);
        qi[d4].y = tof(qr[d4 * 4 + 1]);
        qi[d4].z = tof(qr[d4 * 4 + 2]);
        qi[d4].w = tof(qr[d4 * 4 + 3]);
    }
    int bqi = bq[bhS + sq];

    // 128-bit match mask
    unsigned long long m_lo = 0ull, m_hi = 0ull;
    for (int jj = 0; jj < 64; jj++) {
        if (bqi == __shfl(bk_reg[0], jj, 64)) m_lo |= (1ull << jj);
        if (bqi == __shfl(bk_reg[1], jj, 64)) m_hi |= (1ull << jj);
    }

    // QK^T pass: store masked scores, track 4 partial maxes
    float pm0 = -INFINITY, pm1 = -INFINITY, pm2 = -INFINITY, pm3 = -INFINITY;
    for (int jj = 0; jj < 128; jj += 4) {
        #pragma unroll
        for (int u = 0; u < 4; u++) {
            int j = jj + u;
            const float4* kr = reinterpret_cast<const float4*>(&kv[j][0]);
            float s0 = 0.f, s1 = 0.f, s2 = 0.f, s3 = 0.f;
            #pragma unroll
            for (int d4 = 0; d4 < 16; d4 += 4) {
                float4 k0 = kr[d4], k1 = kr[d4 + 1], k2 = kr[d4 + 2], k3 = kr[d4 + 3];
                s0 += qi[d4].x * k0.x + qi[d4].y * k0.y + qi[d4].z * k0.z + qi[d4].w * k0.w;
                s1 += qi[d4+1].x * k1.x + qi[d4+1].y * k1.y + qi[d4+1].z * k1.z + qi[d4+1].w * k1.w;
                s2 += qi[d4+2].x * k2.x + qi[d4+2].y * k2.y + qi[d4+2].z * k2.z + qi[d4+2].w * k2.w;
                s3 += qi[d4+3].x * k3.x + qi[d4+3].y * k3.y + qi[d4+3].z * k3.z + qi[d4+3].w * k3.w;
            }
            float s = (s0 + s1) + (s2 + s3);
            bool match = (j < 64) ? ((m_lo >> j) & 1ull) : ((m_hi >> (j - 64)) & 1ull);
            float sc = match ? s * 0.125f : -1e9f;
            sx[j][tid] = sc;
            if (u == 0) pm0 = fmaxf(pm0, sc);
            else if (u == 1) pm1 = fmaxf(pm1, sc);
            else if (u == 2) pm2 = fmaxf(pm2, sc);
            else pm3 = fmaxf(pm3, sc);
        }
    }
    float m = fmaxf(fmaxf(pm0, pm1), fmaxf(pm2, pm3));

    // restage V over the K buffer
    __syncthreads();
    for (int r = 0; r < 128; r++) {
        int sk = __shfl(sk_reg[r >> 6], r & 63, 64);
        kv[r][tid] = tof(v[(bhS + sk) * 64 + tid]);
    }
    __syncthreads();

    // PV pass: p_j = exp(sc - m); acc += p*v; l += p; scale at end
    float4 acc[16];
    #pragma unroll
    for (int d4 = 0; d4 < 16; d4++) acc[d4] = make_float4(0.f, 0.f, 0.f, 0.f);
    float l = 0.f;
    for (int j = 0; j < 128; j++) {
        float p = __expf(sx[j][tid] - m);
        l += p;
        const float4* vr = reinterpret_cast<const float4*>(&kv[j][0]);
        #pragma unroll
        for (int d4 = 0; d4 < 16; d4++) {
            float4 vv = vr[d4];
            acc[d4].x += p * vv.x;
            acc[d4].y += p * vv.y;
            acc[d4].z += p * vv.z;
            acc[d4].w += p * vv.w;
        }
    }
    float inv = 1.0f / l;
    OT* orow = o + ((size_t)b * S_ + sq) * 512 + h * 64;
    #pragma unroll
    for (int d4 = 0; d4 < 16; d4++) {
        float ov[4] = { acc[d4].x * inv, acc[d4].y * inv, acc[d4].z * inv, acc[d4].w * inv };
        #pragma unroll
        for (int u = 0; u < 4; u++) {
            if (sizeof(OT) == 2) orow[d4 * 4 + u] = (OT)__float2bfloat16(ov[u]);
            else orow[d4 * 4 + u] = (OT)ov[u];
        }
    }
}

// ---------------------------------------------------------------------------
// LayerNorm per row of [M,512], f32 out (+ optional bf16 copy).
// ---------------------------------------------------------------------------
template<bool BFC>
__global__ __launch_bounds__(256) void ln_k(
    const float* __restrict__ x, const float* __restrict__ g,
    const float* __restrict__ bvec, float* __restrict__ out,
    bf16* __restrict__ bfout)
{
    int row = blockIdx.x;
    int tid = threadIdx.x;
    __shared__ float red[256];
    const float* xr = x + (size_t)row * D_;
    float v0 = xr[tid], v1 = xr[tid + 256];
    red[tid] = v0 + v1;
    __syncthreads();
    for (int off = 128; off > 0; off >>= 1) {
        if (tid < off) red[tid] += red[tid + off];
        __syncthreads();
    }
    float mean = red[0] / 512.f;
    __syncthreads();
    float d0 = v0 - mean, d1 = v1 - mean;
    red[tid] = d0 * d0 + d1 * d1;
    __syncthreads();
    for (int off = 128; off > 0; off >>= 1) {
        if (tid < off) red[tid] += red[tid + off];
        __syncthreads();
    }
    float var = red[0] / 512.f;
    float rs = 1.0f / sqrtf(var + 1e-5f);
    float y0 = d0 * rs * g[tid] + bvec[tid];
    float y1 = d1 * rs * g[tid + 256] + bvec[tid + 256];
    out[(size_t)row * D_ + tid] = y0;
    out[(size_t)row * D_ + tid + 256] = y1;
    if (BFC) {
        bfout[(size_t)row * D_ + tid] = __float2bfloat16(y0);
        bfout[(size_t)row * D_ + tid + 256] = __float2bfloat16(y1);
    }
}

// ---------------------------------------------------------------------------
extern "C" void kernel_launch(void* const* d_in, const int* in_sizes, int n_in,
                              void* d_out, int out_size, void* d_ws, size_t ws_size,
                              hipStream_t stream)
{
    (void)in_sizes; (void)n_in; (void)out_size; (void)ws_size;
    const float* dec   = (const float*)d_in[0];
    const float* enc   = (const float*)d_in[1];
    const float* sa_Wq = (const float*)d_in[2];
    const float* sa_Wk = (const float*)d_in[3];
    const float* sa_Wv = (const float*)d_in[4];
    const float* sa_Wo = (const float*)d_in[5];
    const float* sa_g  = (const float*)d_in[6];
    const float* sa_b  = (const float*)d_in[7];
    const float* sa_rot= (const float*)d_in[8];
    const float* ca_Wq = (const float*)d_in[9];
    const float* ca_Wk = (const float*)d_in[10];
    const float* ca_Wv = (const float*)d_in[11];
    const float* ca_Wo = (const float*)d_in[12];
    const float* ca_g  = (const float*)d_in[13];
    const float* ca_b  = (const float*)d_in[14];
    const float* ca_rot= (const float*)d_in[15];
    const float* ff_W1 = (const float*)d_in[16];
    const float* ff_b1 = (const float*)d_in[17];
    const float* ff_W2 = (const float*)d_in[18];
    const float* ff_b2 = (const float*)d_in[19];
    const float* ff_g  = (const float*)d_in[20];
    const float* ff_b  = (const float*)d_in[21];

    char* ws = (char*)d_ws;
    const size_t MB = 1ull << 20;
    // SA phase (f32)
    float* qb     = (float*)(ws + 0);        // 32MB
    float* kb     = (float*)(ws + 32*MB);    // 32MB
    float* vb     = (float*)(ws + 64*MB);    // 32MB
    float* ob     = (float*)(ws + 96*MB);    // 32MB
    float* act0   = (float*)(ws + 128*MB);   // 32MB (live thru ca_Wo residual)
    bf16*  act0bf = (bf16*)(ws + 160*MB);    // 16MB
    // CA phase overlays (qb..ob dead)
    bf16*  cq     = (bf16*)(ws + 0);         // 16MB
    bf16*  ck     = (bf16*)(ws + 16*MB);     // 16MB
    bf16*  cv     = (bf16*)(ws + 32*MB);     // 16MB
    bf16*  caOut  = (bf16*)(ws + 48*MB);     // 16MB
    bf16*  encbf  = (bf16*)(ws + 64*MB);     // 16MB (after SA attn)
    bf16*  act1bf = (bf16*)(ws + 80*MB);     // 16MB
    float* act1   = (float*)(ws + 96*MB);    // 32MB
    // FF overlays (cq..caOut dead)
    bf16*  hid    = (bf16*)(ws + 0);         // 64MB
    float* ffout  = (float*)(ws + 128*MB);   // 32MB (act0 dead)
    // weights / hash
    bf16*  caWqt  = (bf16*)(ws + 176*MB);
    bf16*  caWkt  = (bf16*)(ws + 176*MB + 512*1024);
    bf16*  caWvt  = (bf16*)(ws + 177*MB);
    bf16*  caWot  = (bf16*)(ws + 177*MB + 512*1024);
    bf16*  ffW1t  = (bf16*)(ws + 178*MB);    // 2MB
    bf16*  ffW2t  = (bf16*)(ws + 180*MB);    // 2MB
    float* wrotq  = (float*)(ws + 182*MB);
    float* wrotk  = (float*)(ws + 182*MB + 512*1024);
    int*   bqb    = (int*)(ws + 183*MB);
    int*   bkb    = (int*)(ws + 183*MB + 512*1024);
    int*   pqb    = (int*)(ws + 184*MB);
    int*   pkb    = (int*)(ws + 184*MB + 512*1024);   // ends at 185MB

    dim3 blk(256);
    const int g512  = (M_ / 128) * (512 / 128);    // 512 blocks
    const int g2048 = (M_ / 128) * (2048 / 128);   // 2048 blocks

    // ---- converters (independent) ----
    wrot_k<<<512, blk, 0, stream>>>(ca_Wq, ca_rot, wrotq);
    wrot_k<<<512, blk, 0, stream>>>(ca_Wk, ca_rot, wrotk);
    convw_k<<<1024, blk, 0, stream>>>(ca_Wq, caWqt, 512, 512);
    convw_k<<<1024, blk, 0, stream>>>(ca_Wk, caWkt, 512, 512);
    convw_k<<<1024, blk, 0, stream>>>(ca_Wv, caWvt, 512, 512);
    convw_k<<<1024, blk, 0, stream>>>(ca_Wo, caWot, 512, 512);
    convw_k<<<4096, blk, 0, stream>>>(ff_W1, ffW1t, 2048, 512);
    convw_k<<<4096, blk, 0, stream>>>(ff_W2, ffW2t, 512, 2048);

    // ---------------- self-attention (f32-class, feeds ca-hash) ----------
    gemm_k<1,0><<<g512, blk, 0, stream>>>(dec, sa_Wq, nullptr, qb, 512, 512);
    gemm_k<1,0><<<g512, blk, 0, stream>>>(dec, sa_Wk, nullptr, kb, 512, 512);
    gemm_k<1,0><<<g512, blk, 0, stream>>>(dec, sa_Wv, nullptr, vb, 512, 512);
    hash_k<<<BH_ * 16, blk, 0, stream>>>(qb, sa_rot, bqb);
    hash_k<<<BH_ * 16, blk, 0, stream>>>(kb, sa_rot, bkb);
    sort_k<<<BH_, dim3(64), 0, stream>>>(bqb, pqb);
    sort_k<<<BH_, dim3(64), 0, stream>>>(bkb, pkb);
    attn_k<float,float><<<BH_ * NC_, dim3(64), 0, stream>>>(qb, kb, vb, bqb, bkb, pqb, pkb, ob);
    gemm_k<0,1><<<g512, blk, 0, stream>>>(ob, sa_Wo, dec, act0, 512, 512);
    ln_k<true><<<M_, blk, 0, stream>>>(act0, sa_g, sa_b, act0, act0bf);

    // ---------------- cross-attention ----------------
    cast_k<<<M_ * 512 / 1024, blk, 0, stream>>>(enc, encbf);
    rhash_k<<<M_, blk, 0, stream>>>(act0, wrotq, bqb);
    rhash_k<<<M_, blk, 0, stream>>>(enc,  wrotk, bkb);
    sort_k<<<BH_, dim3(64), 0, stream>>>(bqb, pqb);
    sort_k<<<BH_, dim3(64), 0, stream>>>(bkb, pkb);
    mgemm_k<2,0,false,false><<<g512, blk, 0, stream>>>((const short*)act0bf, (const short*)caWqt, nullptr, nullptr, cq, 512, 512);
    mgemm_k<2,0,false,false><<<g512, blk, 0, stream>>>((const short*)encbf, (const short*)caWkt, nullptr, nullptr, ck, 512, 512);
    mgemm_k<2,0,false,false><<<g512, blk, 0, stream>>>((const short*)encbf, (const short*)caWvt, nullptr, nullptr, cv, 512, 512);
    attn_k<bf16,bf16><<<BH_ * NC_, dim3(64), 0, stream>>>(cq, ck, cv, bqb, bkb, pqb, pkb, caOut);
    mgemm_k<0,1,false,false><<<g512, blk, 0, stream>>>((const short*)caOut, (const short*)caWot, nullptr, act0, act1, 512, 512);
    ln_k<true><<<M_, blk, 0, stream>>>(act1, ca_g, ca_b, act1, act1bf);

    // ---------------- feed-forward ----------------
    mgemm_k<1,0,true,true><<<g2048, blk, 0, stream>>>((const short*)act1bf, (const short*)ffW1t, ff_b1, nullptr, hid, 2048, 512);
    mgemm_k<0,1,true,false><<<g512, blk, 0, stream>>>((const short*)hid, (const short*)ffW2t, ff_b2, act1, ffout, 512, 2048);
    ln_k<false><<<M_, blk, 0, stream>>>(ffout, ff_g, ff_b, (float*)d_out, nullptr);
}

// Round 5
// 2751.883 us; speedup vs baseline: 1.6218x; 1.1819x over previous
//
#include <hip/hip_runtime.h>
#include <hip/hip_bf16.h>
#include <math.h>

typedef __hip_bfloat16 bf16;

#define B_ 4
#define S_ 4096
#define D_ 512
#define H_ 8
#define NC_ 64
#define M_ (B_*S_)     // 16384
#define BH_ (B_*H_)    // 32

typedef __attribute__((ext_vector_type(8))) short bfrag;   // 8 bf16 (4 VGPRs)
typedef __attribute__((ext_vector_type(4))) float facc;    // 4 f32 acc

static __device__ __forceinline__ float tof(float x){ return x; }
static __device__ __forceinline__ float tof(bf16 x){ return __bfloat162float(x); }

static __device__ __forceinline__ float4 ld4g(const float* p) {
    return *reinterpret_cast<const float4*>(p);
}
static __device__ __forceinline__ float4 ld4g(const bf16* p) {
    short4 s = *reinterpret_cast<const short4*>(p);
    float4 r;
    r.x = __bfloat162float(*reinterpret_cast<const bf16*>(&s.x));
    r.y = __bfloat162float(*reinterpret_cast<const bf16*>(&s.y));
    r.z = __bfloat162float(*reinterpret_cast<const bf16*>(&s.z));
    r.w = __bfloat162float(*reinterpret_cast<const bf16*>(&s.w));
    return r;
}
static __device__ __forceinline__ void st4(float* p, float4 v) {
    *reinterpret_cast<float4*>(p) = v;
}
static __device__ __forceinline__ void st4(bf16* p, float4 v) {
    bf16 b0 = __float2bfloat16(v.x), b1 = __float2bfloat16(v.y);
    bf16 b2 = __float2bfloat16(v.z), b3 = __float2bfloat16(v.w);
    short4 s;
    s.x = *reinterpret_cast<short*>(&b0);
    s.y = *reinterpret_cast<short*>(&b1);
    s.z = *reinterpret_cast<short*>(&b2);
    s.w = *reinterpret_cast<short*>(&b3);
    *reinterpret_cast<short4*>(p) = s;
}

#define GLL(gp, lp) __builtin_amdgcn_global_load_lds( \
    (const __attribute__((address_space(1))) void*)(gp), \
    (__attribute__((address_space(3))) void*)(lp), 16, 0, 0)

// ---------------------------------------------------------------------------
// f32 VALU GEMM (hash-feeding SA path; f32-class accuracy required).
// OUTMODE: 0 = f32 row-major [M,N], 1 = f32 qkv-scatter [B,H,S,64]
// RES:     0 = none, 1 = f32 residual row-major [M,N]
// ---------------------------------------------------------------------------
template<int OUTMODE, int RES>
__global__ __launch_bounds__(256) void gemm_k(
    const float* __restrict__ A, const float* __restrict__ Bw,
    const float* __restrict__ res, float* __restrict__ out, int N, int K)
{
    const int BM = 128, BN = 128, BK = 16;
    __shared__ float As[BM][BK + 1];
    __shared__ float Bs[BK][BN + 1];

    int tid = threadIdx.x;
    int nbx = N / BN;
    int bx = blockIdx.x % nbx;
    int by = blockIdx.x / nbx;
    int row0 = by * BM, col0 = bx * BN;
    int ty = tid >> 4;   // 0..15
    int tx = tid & 15;   // 0..15

    float acc[8][8];
    #pragma unroll
    for (int i = 0; i < 8; i++)
        #pragma unroll
        for (int j = 0; j < 8; j++) acc[i][j] = 0.f;

    for (int k0 = 0; k0 < K; k0 += BK) {
        {
            int r = tid >> 1, cb = (tid & 1) * 8;
            const float* ap = A + (size_t)(row0 + r) * K + k0 + cb;
            #pragma unroll
            for (int i = 0; i < 8; i++) As[r][cb + i] = ap[i];
        }
        {
            int r = tid >> 4, cb = (tid & 15) * 8;
            const float* bp = Bw + (size_t)(k0 + r) * N + col0 + cb;
            #pragma unroll
            for (int i = 0; i < 8; i++) Bs[r][cb + i] = bp[i];
        }
        __syncthreads();
        #pragma unroll
        for (int kk = 0; kk < BK; kk++) {
            float a[8], bb[8];
            #pragma unroll
            for (int i = 0; i < 8; i++) a[i] = As[ty * 8 + i][kk];
            #pragma unroll
            for (int j = 0; j < 8; j++) bb[j] = Bs[kk][tx + j * 16];
            #pragma unroll
            for (int i = 0; i < 8; i++)
                #pragma unroll
                for (int j = 0; j < 8; j++) acc[i][j] += a[i] * bb[j];
        }
        __syncthreads();
    }

    #pragma unroll
    for (int i = 0; i < 8; i++) {
        int r = row0 + ty * 8 + i;
        #pragma unroll
        for (int j = 0; j < 8; j++) {
            int c = col0 + tx + j * 16;
            float v = acc[i][j];
            if (RES == 1) v += res[(size_t)r * N + c];
            if (OUTMODE == 0) {
                out[(size_t)r * N + c] = v;
            } else {
                int b = r >> 12, s = r & (S_ - 1);
                int h = c >> 6, kk2 = c & 63;
                out[((size_t)(b * H_ + h) * S_ + s) * 64 + kk2] = v;
            }
        }
    }
}

// ---------------------------------------------------------------------------
// bf16 MFMA GEMM (post-hash smooth path). A: [M,K] bf16 RM. Bt: [N,K] bf16.
// ---------------------------------------------------------------------------
template<int OUTMODE, int RES, bool BIAS, bool RELU>
__global__ __launch_bounds__(256) void mgemm_k(
    const short* __restrict__ A, const short* __restrict__ Bt,
    const float* __restrict__ bias, const float* __restrict__ res,
    void* __restrict__ out, int N, int K)
{
    __shared__ short As[128 * 32];
    __shared__ short Bs[128 * 32];

    int tid = threadIdx.x;
    int wave = tid >> 6, lane = tid & 63;
    int nbx = N >> 7;
    int bx = blockIdx.x % nbx, by = blockIdx.x / nbx;
    int row0 = by << 7, col0 = bx << 7;
    int wr = wave >> 1, wc = wave & 1;   // 64x64 wave tile
    int fr = lane & 15, fq = lane >> 4;

    facc acc[4][4];
    facc zero = {0.f, 0.f, 0.f, 0.f};
    #pragma unroll
    for (int m = 0; m < 4; m++)
        #pragma unroll
        for (int n = 0; n < 4; n++) acc[m][n] = zero;

    const short* gA = A + (size_t)(row0 + (wave << 5) + (lane >> 2)) * K + ((lane & 3) << 3);
    const short* gB = Bt + (size_t)(col0 + (wave << 5) + (lane >> 2)) * K + ((lane & 3) << 3);

    for (int k0 = 0; k0 < K; k0 += 32) {
        GLL(gA + k0,                 &As[wave << 10]);
        GLL(gA + k0 + (size_t)16 * K, &As[(wave << 10) + 512]);
        GLL(gB + k0,                 &Bs[wave << 10]);
        GLL(gB + k0 + (size_t)16 * K, &Bs[(wave << 10) + 512]);
        __syncthreads();

        bfrag av[4], bv[4];
        #pragma unroll
        for (int m = 0; m < 4; m++)
            av[m] = *reinterpret_cast<const bfrag*>(&As[(((wr << 6) + (m << 4) + fr) << 5) + (fq << 3)]);
        #pragma unroll
        for (int n = 0; n < 4; n++)
            bv[n] = *reinterpret_cast<const bfrag*>(&Bs[(((wc << 6) + (n << 4) + fr) << 5) + (fq << 3)]);
        #pragma unroll
        for (int m = 0; m < 4; m++)
            #pragma unroll
            for (int n = 0; n < 4; n++)
                acc[m][n] = __builtin_amdgcn_mfma_f32_16x16x32_bf16(av[m], bv[n], acc[m][n], 0, 0, 0);
        __syncthreads();
    }

    #pragma unroll
    for (int m = 0; m < 4; m++) {
        #pragma unroll
        for (int n = 0; n < 4; n++) {
            #pragma unroll
            for (int r = 0; r < 4; r++) {
                int row = row0 + (wr << 6) + (m << 4) + (fq << 2) + r;
                int col = col0 + (wc << 6) + (n << 4) + fr;
                float v = acc[m][n][r];
                if (BIAS) v += bias[col];
                if (RELU) v = fmaxf(v, 0.f);
                if (RES == 1) v += res[(size_t)row * N + col];
                if (OUTMODE == 0) {
                    ((float*)out)[(size_t)row * N + col] = v;
                } else if (OUTMODE == 1) {
                    ((bf16*)out)[(size_t)row * N + col] = __float2bfloat16(v);
                } else {
                    int b = row >> 12, s = row & (S_ - 1);
                    int h = col >> 6, kk2 = col & 63;
                    ((bf16*)out)[(((size_t)(b * H_ + h) * S_ + s) << 6) + kk2] = __float2bfloat16(v);
                }
            }
        }
    }
}

// ---------------------------------------------------------------------------
// Weight converters
// ---------------------------------------------------------------------------
__global__ __launch_bounds__(256) void convw_k(
    const float* __restrict__ W, bf16* __restrict__ Wt, int N, int K)
{
    int i = blockIdx.x * 256 + threadIdx.x;
    int n = i / K, k = i % K;
    Wt[i] = __float2bfloat16(W[(size_t)k * N + n]);
}

__global__ __launch_bounds__(256) void wrot_k(
    const float* __restrict__ W, const float* __restrict__ rot,
    float* __restrict__ wrot)
{
    int d = blockIdx.x, t = threadIdx.x;
    int h = t >> 5, j = t & 31;
    float a = 0.f;
    #pragma unroll
    for (int k = 0; k < 64; k++)
        a += W[(size_t)(d * H_ + h) * 64 + k] * rot[(size_t)(h * 64 + k) * 32 + j];
    wrot[(size_t)d * 256 + t] = a;
}

__global__ __launch_bounds__(256) void cast_k(
    const float* __restrict__ x, bf16* __restrict__ y)
{
    size_t i = ((size_t)blockIdx.x * 256 + threadIdx.x) * 4;
    float4 v = *reinterpret_cast<const float4*>(x + i);
    y[i]     = __float2bfloat16(v.x);
    y[i + 1] = __float2bfloat16(v.y);
    y[i + 2] = __float2bfloat16(v.z);
    y[i + 3] = __float2bfloat16(v.w);
}

// ---------------------------------------------------------------------------
// SA hash
// ---------------------------------------------------------------------------
__global__ __launch_bounds__(256) void hash_k(
    const float* __restrict__ t, const float* __restrict__ rot,
    int* __restrict__ bucket)
{
    int bh = blockIdx.x >> 4;
    int st = blockIdx.x & 15;
    int h = bh % H_;
    __shared__ float rs[64][32];
    int tid = threadIdx.x;
    for (int e = tid; e < 2048; e += 256)
        rs[e >> 5][e & 31] = rot[h * 2048 + e];
    __syncthreads();

    int s = st * 256 + tid;
    const float* qr = t + ((size_t)bh * S_ + s) * 64;
    float qv[64];
    #pragma unroll
    for (int i = 0; i < 64; i++) qv[i] = qr[i];
    float r[32];
    #pragma unroll
    for (int j = 0; j < 32; j++) {
        float a = 0.f;
        #pragma unroll
        for (int kk = 0; kk < 64; kk++) a += qv[kk] * rs[kk][j];
        r[j] = a;
    }
    float best = -INFINITY; int bi = 0;
    #pragma unroll
    for (int j = 0; j < 32; j++) { if (r[j] > best) { best = r[j]; bi = j; } }
    #pragma unroll
    for (int j = 0; j < 32; j++) { float v = -r[j]; if (v > best) { best = v; bi = 32 + j; } }
    bucket[(size_t)bh * S_ + s] = bi;
}

// ---------------------------------------------------------------------------
// CA hash fused from row-major activations
// ---------------------------------------------------------------------------
__global__ __launch_bounds__(256) void rhash_k(
    const float* __restrict__ x, const float* __restrict__ wrot,
    int* __restrict__ bucket)
{
    __shared__ float xs[512];
    int tid = threadIdx.x;
    const float* xr = x + (size_t)blockIdx.x * 512;
    xs[tid] = xr[tid];
    xs[tid + 256] = xr[tid + 256];
    __syncthreads();
    float a = 0.f;
    #pragma unroll 8
    for (int d = 0; d < 512; d++) a += xs[d] * wrot[(size_t)d * 256 + tid];

    int j = tid & 31;
    float bv_ = a; int bi = j;
    float nb = -a;
    if (nb > bv_) { bv_ = nb; bi = 32 + j; }
    #pragma unroll
    for (int off = 1; off < 32; off <<= 1) {
        float ov = __shfl_xor(bv_, off, 64);
        int oi = __shfl_xor(bi, off, 64);
        if (ov > bv_ || (ov == bv_ && oi < bi)) { bv_ = ov; bi = oi; }
    }
    if (j == 0) {
        int b = blockIdx.x >> 12, s = blockIdx.x & (S_ - 1), h = tid >> 5;
        bucket[((size_t)(b * H_ + h)) * S_ + s] = bi;
    }
}

// ---------------------------------------------------------------------------
// Stable counting sort by bucket per (b,h) — argsort(bucket*S + pos).
// ---------------------------------------------------------------------------
__global__ __launch_bounds__(64) void sort_k(
    const int* __restrict__ bucket, int* __restrict__ perm)
{
    int bh = blockIdx.x;
    __shared__ int lb[S_];
    int tid = threadIdx.x;
    for (int i = tid; i < S_; i += 64) lb[i] = bucket[(size_t)bh * S_ + i];
    __syncthreads();
    int cnt = 0;
    for (int i = 0; i < S_; i++) cnt += (lb[i] == tid) ? 1 : 0;
    int incl = cnt;
    #pragma unroll
    for (int off = 1; off < 64; off <<= 1) {
        int n = __shfl_up(incl, off, 64);
        if (tid >= off) incl += n;
    }
    int idx = incl - cnt;
    int* pr = perm + (size_t)bh * S_;
    for (int i = 0; i < S_; i++)
        if (lb[i] == tid) pr[idx++] = i;
}

// ---------------------------------------------------------------------------
// Chunked LSH attention, round 5: 4 waves/block, quad-per-query.
// Thread (q = tid>>2, u = tid&3); u owns dims [u*16, u*16+16).
// QK^T: per-lane partial dots over 16 dims for all 128 keys (4 groups of
// 32), 2-step shfl_xor butterfly -> lane owns final scores of 32 keys
// j(g,u,t) = g*32 + (u>>1)*16 + (u&1)*8 + t. Mask/max/exp/denominator
// per-lane + quad shfl reductions: semantics identical to -1e9-masked
// softmax incl. uniform fallback. PV: uniform j loop, p_j shfl'd from its
// owner lane (fully unrolled -> compile-time register index), acc on own
// 16 dims. LDS 33 KiB (V restaged over K) + VGPR<=128 -> 16 waves/CU.
// ---------------------------------------------------------------------------
template<typename T, typename OT>
__global__ __launch_bounds__(256, 4) void attn_k(
    const T* __restrict__ q, const T* __restrict__ k,
    const T* __restrict__ v, const int* __restrict__ bq,
    const int* __restrict__ bk, const int* __restrict__ permq,
    const int* __restrict__ permk, OT* __restrict__ o)
{
    int c = blockIdx.x % NC_;
    int bh = blockIdx.x / NC_;
    int b = bh / H_, h = bh % H_;
    __shared__ float kv[128][64];
    __shared__ int skx[128];
    __shared__ int bkx[128];
    int tid = threadIdx.x;
    const int qq = tid >> 2, u = tid & 3;
    const size_t bhS = (size_t)bh * S_;

    if (tid < 128) {
        int sidx = (tid < 64) ? (((c + NC_ - 1) & (NC_ - 1)) * 64 + tid)
                              : (c * 64 + (tid - 64));
        int sk = permk[bhS + sidx];
        skx[tid] = sk;
        bkx[tid] = bk[bhS + sk];
    }
    __syncthreads();

    // stage K: 8 passes x 16 rows (16 lanes x float4 per row)
    {
        int rr = tid >> 4, c4 = (tid & 15) << 2;
        #pragma unroll
        for (int pass = 0; pass < 8; pass++) {
            int row = pass * 16 + rr;
            *reinterpret_cast<float4*>(&kv[row][c4]) =
                ld4g(k + (bhS + skx[row]) * 64 + c4);
        }
    }

    int sq = permq[bhS + c * 64 + qq];
    float4 qv[4];
    {
        const T* qr = q + (bhS + sq) * 64 + u * 16;
        #pragma unroll
        for (int i = 0; i < 4; i++) qv[i] = ld4g(qr + i * 4);
    }
    int bqi = bq[bhS + sq];
    __syncthreads();

    // QK^T + butterfly reduce + mask
    float p[32];
    #pragma unroll
    for (int g = 0; g < 4; g++) {
        float part[32];
        #pragma unroll
        for (int t = 0; t < 32; t++) {
            const float4* kr = reinterpret_cast<const float4*>(&kv[g * 32 + t][u << 4]);
            float4 k0 = kr[0], k1 = kr[1], k2 = kr[2], k3 = kr[3];
            float s0 = qv[0].x * k0.x + qv[0].y * k0.y + qv[0].z * k0.z + qv[0].w * k0.w;
            float s1 = qv[1].x * k1.x + qv[1].y * k1.y + qv[1].z * k1.z + qv[1].w * k1.w;
            float s2 = qv[2].x * k2.x + qv[2].y * k2.y + qv[2].z * k2.z + qv[2].w * k2.w;
            float s3 = qv[3].x * k3.x + qv[3].y * k3.y + qv[3].z * k3.z + qv[3].w * k3.w;
            part[t] = (s0 + s1) + (s2 + s3);
        }
        float keep[16];
        #pragma unroll
        for (int t = 0; t < 16; t++) {
            float lo = __shfl_xor(part[t], 2, 64);
            float hi = __shfl_xor(part[16 + t], 2, 64);
            keep[t] = (u < 2) ? part[t] + lo : part[16 + t] + hi;
        }
        #pragma unroll
        for (int t = 0; t < 8; t++) {
            float lo = __shfl_xor(keep[t], 1, 64);
            float hi = __shfl_xor(keep[8 + t], 1, 64);
            float s = ((u & 1) == 0) ? keep[t] + lo : keep[8 + t] + hi;
            int j = g * 32 + (u >> 1) * 16 + (u & 1) * 8 + t;
            p[g * 8 + t] = (bqi == bkx[j]) ? s * 0.125f : -1e9f;
        }
    }

    // softmax pieces (quad-wide)
    float m = -INFINITY;
    #pragma unroll
    for (int i = 0; i < 32; i++) m = fmaxf(m, p[i]);
    m = fmaxf(m, __shfl_xor(m, 1, 64));
    m = fmaxf(m, __shfl_xor(m, 2, 64));
    float l = 0.f;
    #pragma unroll
    for (int i = 0; i < 32; i++) { p[i] = __expf(p[i] - m); l += p[i]; }
    l += __shfl_xor(l, 1, 64);
    l += __shfl_xor(l, 2, 64);

    // restage V over K buffer
    __syncthreads();
    {
        int rr = tid >> 4, c4 = (tid & 15) << 2;
        #pragma unroll
        for (int pass = 0; pass < 8; pass++) {
            int row = pass * 16 + rr;
            *reinterpret_cast<float4*>(&kv[row][c4]) =
                ld4g(v + (bhS + skx[row]) * 64 + c4);
        }
    }
    __syncthreads();

    // PV: uniform j loop; p_j shfl'd from owner lane within the quad
    float4 acc0 = make_float4(0.f, 0.f, 0.f, 0.f);
    float4 acc1 = make_float4(0.f, 0.f, 0.f, 0.f);
    float4 acc2 = make_float4(0.f, 0.f, 0.f, 0.f);
    float4 acc3 = make_float4(0.f, 0.f, 0.f, 0.f);
    int base = tid & ~3;
    #pragma unroll
    for (int j = 0; j < 128; j++) {
        const int uo = ((j >> 3) & 1) | (((j >> 4) & 1) << 1);
        const int slot = ((j >> 5) << 3) | (j & 7);
        float pj = __shfl(p[slot], base + uo, 64);
        const float4* vr = reinterpret_cast<const float4*>(&kv[j][u << 4]);
        float4 v0 = vr[0], v1 = vr[1], v2 = vr[2], v3 = vr[3];
        acc0.x += pj * v0.x; acc0.y += pj * v0.y; acc0.z += pj * v0.z; acc0.w += pj * v0.w;
        acc1.x += pj * v1.x; acc1.y += pj * v1.y; acc1.z += pj * v1.z; acc1.w += pj * v1.w;
        acc2.x += pj * v2.x; acc2.y += pj * v2.y; acc2.z += pj * v2.z; acc2.w += pj * v2.w;
        acc3.x += pj * v3.x; acc3.y += pj * v3.y; acc3.z += pj * v3.z; acc3.w += pj * v3.w;
    }
    float inv = 1.0f / l;
    OT* orow = o + ((size_t)b * S_ + sq) * 512 + h * 64 + (u << 4);
    st4(orow + 0,  make_float4(acc0.x * inv, acc0.y * inv, acc0.z * inv, acc0.w * inv));
    st4(orow + 4,  make_float4(acc1.x * inv, acc1.y * inv, acc1.z * inv, acc1.w * inv));
    st4(orow + 8,  make_float4(acc2.x * inv, acc2.y * inv, acc2.z * inv, acc2.w * inv));
    st4(orow + 12, make_float4(acc3.x * inv, acc3.y * inv, acc3.z * inv, acc3.w * inv));
}

// ---------------------------------------------------------------------------
// LayerNorm per row of [M,512], f32 out (+ optional bf16 copy).
// ---------------------------------------------------------------------------
template<bool BFC>
__global__ __launch_bounds__(256) void ln_k(
    const float* __restrict__ x, const float* __restrict__ g,
    const float* __restrict__ bvec, float* __restrict__ out,
    bf16* __restrict__ bfout)
{
    int row = blockIdx.x;
    int tid = threadIdx.x;
    __shared__ float red[256];
    const float* xr = x + (size_t)row * D_;
    float v0 = xr[tid], v1 = xr[tid + 256];
    red[tid] = v0 + v1;
    __syncthreads();
    for (int off = 128; off > 0; off >>= 1) {
        if (tid < off) red[tid] += red[tid + off];
        __syncthreads();
    }
    float mean = red[0] / 512.f;
    __syncthreads();
    float d0 = v0 - mean, d1 = v1 - mean;
    red[tid] = d0 * d0 + d1 * d1;
    __syncthreads();
    for (int off = 128; off > 0; off >>= 1) {
        if (tid < off) red[tid] += red[tid + off];
        __syncthreads();
    }
    float var = red[0] / 512.f;
    float rs = 1.0f / sqrtf(var + 1e-5f);
    float y0 = d0 * rs * g[tid] + bvec[tid];
    float y1 = d1 * rs * g[tid + 256] + bvec[tid + 256];
    out[(size_t)row * D_ + tid] = y0;
    out[(size_t)row * D_ + tid + 256] = y1;
    if (BFC) {
        bfout[(size_t)row * D_ + tid] = __float2bfloat16(y0);
        bfout[(size_t)row * D_ + tid + 256] = __float2bfloat16(y1);
    }
}

// ---------------------------------------------------------------------------
extern "C" void kernel_launch(void* const* d_in, const int* in_sizes, int n_in,
                              void* d_out, int out_size, void* d_ws, size_t ws_size,
                              hipStream_t stream)
{
    (void)in_sizes; (void)n_in; (void)out_size; (void)ws_size;
    const float* dec   = (const float*)d_in[0];
    const float* enc   = (const float*)d_in[1];
    const float* sa_Wq = (const float*)d_in[2];
    const float* sa_Wk = (const float*)d_in[3];
    const float* sa_Wv = (const float*)d_in[4];
    const float* sa_Wo = (const float*)d_in[5];
    const float* sa_g  = (const float*)d_in[6];
    const float* sa_b  = (const float*)d_in[7];
    const float* sa_rot= (const float*)d_in[8];
    const float* ca_Wq = (const float*)d_in[9];
    const float* ca_Wk = (const float*)d_in[10];
    const float* ca_Wv = (const float*)d_in[11];
    const float* ca_Wo = (const float*)d_in[12];
    const float* ca_g  = (const float*)d_in[13];
    const float* ca_b  = (const float*)d_in[14];
    const float* ca_rot= (const float*)d_in[15];
    const float* ff_W1 = (const float*)d_in[16];
    const float* ff_b1 = (const float*)d_in[17];
    const float* ff_W2 = (const float*)d_in[18];
    const float* ff_b2 = (const float*)d_in[19];
    const float* ff_g  = (const float*)d_in[20];
    const float* ff_b  = (const float*)d_in[21];

    char* ws = (char*)d_ws;
    const size_t MB = 1ull << 20;
    // SA phase (f32)
    float* qb     = (float*)(ws + 0);        // 32MB
    float* kb     = (float*)(ws + 32*MB);    // 32MB
    float* vb     = (float*)(ws + 64*MB);    // 32MB
    float* ob     = (float*)(ws + 96*MB);    // 32MB
    float* act0   = (float*)(ws + 128*MB);   // 32MB (live thru ca_Wo residual)
    bf16*  act0bf = (bf16*)(ws + 160*MB);    // 16MB
    // CA phase overlays (qb..ob dead)
    bf16*  cq     = (bf16*)(ws + 0);         // 16MB
    bf16*  ck     = (bf16*)(ws + 16*MB);     // 16MB
    bf16*  cv     = (bf16*)(ws + 32*MB);     // 16MB
    bf16*  caOut  = (bf16*)(ws + 48*MB);     // 16MB
    bf16*  encbf  = (bf16*)(ws + 64*MB);     // 16MB (after SA attn)
    bf16*  act1bf = (bf16*)(ws + 80*MB);     // 16MB
    float* act1   = (float*)(ws + 96*MB);    // 32MB
    // FF overlays (cq..caOut dead)
    bf16*  hid    = (bf16*)(ws + 0);         // 64MB
    float* ffout  = (float*)(ws + 128*MB);   // 32MB (act0 dead)
    // weights / hash
    bf16*  caWqt  = (bf16*)(ws + 176*MB);
    bf16*  caWkt  = (bf16*)(ws + 176*MB + 512*1024);
    bf16*  caWvt  = (bf16*)(ws + 177*MB);
    bf16*  caWot  = (bf16*)(ws + 177*MB + 512*1024);
    bf16*  ffW1t  = (bf16*)(ws + 178*MB);    // 2MB
    bf16*  ffW2t  = (bf16*)(ws + 180*MB);    // 2MB
    float* wrotq  = (float*)(ws + 182*MB);
    float* wrotk  = (float*)(ws + 182*MB + 512*1024);
    int*   bqb    = (int*)(ws + 183*MB);
    int*   bkb    = (int*)(ws + 183*MB + 512*1024);
    int*   pqb    = (int*)(ws + 184*MB);
    int*   pkb    = (int*)(ws + 184*MB + 512*1024);   // ends at 185MB

    dim3 blk(256);
    const int g512  = (M_ / 128) * (512 / 128);    // 512 blocks
    const int g2048 = (M_ / 128) * (2048 / 128);   // 2048 blocks

    // ---- converters (independent) ----
    wrot_k<<<512, blk, 0, stream>>>(ca_Wq, ca_rot, wrotq);
    wrot_k<<<512, blk, 0, stream>>>(ca_Wk, ca_rot, wrotk);
    convw_k<<<1024, blk, 0, stream>>>(ca_Wq, caWqt, 512, 512);
    convw_k<<<1024, blk, 0, stream>>>(ca_Wk, caWkt, 512, 512);
    convw_k<<<1024, blk, 0, stream>>>(ca_Wv, caWvt, 512, 512);
    convw_k<<<1024, blk, 0, stream>>>(ca_Wo, caWot, 512, 512);
    convw_k<<<4096, blk, 0, stream>>>(ff_W1, ffW1t, 2048, 512);
    convw_k<<<4096, blk, 0, stream>>>(ff_W2, ffW2t, 512, 2048);

    // ---------------- self-attention (f32-class, feeds ca-hash) ----------
    gemm_k<1,0><<<g512, blk, 0, stream>>>(dec, sa_Wq, nullptr, qb, 512, 512);
    gemm_k<1,0><<<g512, blk, 0, stream>>>(dec, sa_Wk, nullptr, kb, 512, 512);
    gemm_k<1,0><<<g512, blk, 0, stream>>>(dec, sa_Wv, nullptr, vb, 512, 512);
    hash_k<<<BH_ * 16, blk, 0, stream>>>(qb, sa_rot, bqb);
    hash_k<<<BH_ * 16, blk, 0, stream>>>(kb, sa_rot, bkb);
    sort_k<<<BH_, dim3(64), 0, stream>>>(bqb, pqb);
    sort_k<<<BH_, dim3(64), 0, stream>>>(bkb, pkb);
    attn_k<float,float><<<BH_ * NC_, blk, 0, stream>>>(qb, kb, vb, bqb, bkb, pqb, pkb, ob);
    gemm_k<0,1><<<g512, blk, 0, stream>>>(ob, sa_Wo, dec, act0, 512, 512);
    ln_k<true><<<M_, blk, 0, stream>>>(act0, sa_g, sa_b, act0, act0bf);

    // ---------------- cross-attention ----------------
    cast_k<<<M_ * 512 / 1024, blk, 0, stream>>>(enc, encbf);
    rhash_k<<<M_, blk, 0, stream>>>(act0, wrotq, bqb);
    rhash_k<<<M_, blk, 0, stream>>>(enc,  wrotk, bkb);
    sort_k<<<BH_, dim3(64), 0, stream>>>(bqb, pqb);
    sort_k<<<BH_, dim3(64), 0, stream>>>(bkb, pkb);
    mgemm_k<2,0,false,false><<<g512, blk, 0, stream>>>((const short*)act0bf, (const short*)caWqt, nullptr, nullptr, cq, 512, 512);
    mgemm_k<2,0,false,false><<<g512, blk, 0, stream>>>((const short*)encbf, (const short*)caWkt, nullptr, nullptr, ck, 512, 512);
    mgemm_k<2,0,false,false><<<g512, blk, 0, stream>>>((const short*)encbf, (const short*)caWvt, nullptr, nullptr, cv, 512, 512);
    attn_k<bf16,bf16><<<BH_ * NC_, blk, 0, stream>>>(cq, ck, cv, bqb, bkb, pqb, pkb, caOut);
    mgemm_k<0,1,false,false><<<g512, blk, 0, stream>>>((const short*)caOut, (const short*)caWot, nullptr, act0, act1, 512, 512);
    ln_k<true><<<M_, blk, 0, stream>>>(act1, ca_g, ca_b, act1, act1bf);

    // ---------------- feed-forward ----------------
    mgemm_k<1,0,true,true><<<g2048, blk, 0, stream>>>((const short*)act1bf, (const short*)ffW1t, ff_b1, nullptr, hid, 2048, 512);
    mgemm_k<0,1,true,false><<<g512, blk, 0, stream>>>((const short*)hid, (const short*)ffW2t, ff_b2, act1, ffout, 512, 2048);
    ln_k<false><<<M_, blk, 0, stream>>>(ffout, ff_g, ff_b, (float*)d_out, nullptr);
}

// Round 6
// 2332.475 us; speedup vs baseline: 1.9134x; 1.1798x over previous
//
#include <hip/hip_runtime.h>
#include <hip/hip_bf16.h>
#include <math.h>

typedef __hip_bfloat16 bf16;

#define B_ 4
#define S_ 4096
#define D_ 512
#define H_ 8
#define NC_ 64
#define M_ (B_*S_)     // 16384
#define BH_ (B_*H_)    // 32

typedef __attribute__((ext_vector_type(8))) short bfrag;   // 8 bf16 (4 VGPRs)
typedef __attribute__((ext_vector_type(4))) float facc;    // 4 f32 acc

static __device__ __forceinline__ float tof(float x){ return x; }
static __device__ __forceinline__ float tof(bf16 x){ return __bfloat162float(x); }

static __device__ __forceinline__ float4 ld4g(const float* p) {
    return *reinterpret_cast<const float4*>(p);
}
static __device__ __forceinline__ float4 ld4g(const bf16* p) {
    short4 s = *reinterpret_cast<const short4*>(p);
    float4 r;
    r.x = __bfloat162float(*reinterpret_cast<const bf16*>(&s.x));
    r.y = __bfloat162float(*reinterpret_cast<const bf16*>(&s.y));
    r.z = __bfloat162float(*reinterpret_cast<const bf16*>(&s.z));
    r.w = __bfloat162float(*reinterpret_cast<const bf16*>(&s.w));
    return r;
}
static __device__ __forceinline__ void st4(float* p, float4 v) {
    *reinterpret_cast<float4*>(p) = v;
}
static __device__ __forceinline__ void st4(bf16* p, float4 v) {
    bf16 b0 = __float2bfloat16(v.x), b1 = __float2bfloat16(v.y);
    bf16 b2 = __float2bfloat16(v.z), b3 = __float2bfloat16(v.w);
    short4 s;
    s.x = *reinterpret_cast<short*>(&b0);
    s.y = *reinterpret_cast<short*>(&b1);
    s.z = *reinterpret_cast<short*>(&b2);
    s.w = *reinterpret_cast<short*>(&b3);
    *reinterpret_cast<short4*>(p) = s;
}

#define GLL(gp, lp) __builtin_amdgcn_global_load_lds( \
    (const __attribute__((address_space(1))) void*)(gp), \
    (__attribute__((address_space(3))) void*)(lp), 16, 0, 0)

// ---------------------------------------------------------------------------
// f32 VALU GEMM (hash-feeding paths; f32-class accuracy required).
// BK=32, global_load_lds staging (linear lane->LDS mapping = natural
// row-major tile). LDS reads are broadcast/conflict-free by construction.
// OUTMODE: 0 = f32 row-major [M,N], 1 = f32 qkv-scatter [B,H,S,64]
// RES:     0 = none, 1 = f32 residual row-major [M,N]
// ---------------------------------------------------------------------------
template<int OUTMODE, int RES>
__global__ __launch_bounds__(256) void gemm_k(
    const float* __restrict__ A, const float* __restrict__ Bw,
    const float* __restrict__ res, float* __restrict__ out, int N, int K)
{
    const int BK = 32;
    __shared__ float As[128 * 32];   // [row][k] row-major
    __shared__ float Bs[32 * 128];   // [k][col] row-major

    int tid = threadIdx.x;
    int wave = tid >> 6;
    int nbx = N >> 7;
    int bx = blockIdx.x % nbx;
    int by = blockIdx.x / nbx;
    int row0 = bx == bx ? by << 7 : 0;  // by*128
    int col0 = bx << 7;
    int ty = tid >> 4;   // 0..15
    int tx = tid & 15;   // 0..15

    float acc[8][8];
    #pragma unroll
    for (int i = 0; i < 8; i++)
        #pragma unroll
        for (int j = 0; j < 8; j++) acc[i][j] = 0.f;

    for (int k0 = 0; k0 < K; k0 += BK) {
        // A tile 128x32 f32 (16KB): 4 GLL calls, elem4 e = c*256+tid,
        // row=e>>3, col4=(e&7)*4 ; LDS offset = e*16B (linear) = natural RM.
        #pragma unroll
        for (int c = 0; c < 4; c++) {
            int e = c * 256 + tid;
            GLL(A + (size_t)(row0 + (e >> 3)) * K + k0 + ((e & 7) << 2),
                &As[c * 1024 + (wave << 8)]);
        }
        // B tile 32x128 f32 (16KB): row=e>>5, col4=(e&31)*4.
        #pragma unroll
        for (int c = 0; c < 4; c++) {
            int e = c * 256 + tid;
            GLL(Bw + (size_t)(k0 + (e >> 5)) * N + col0 + ((e & 31) << 2),
                &Bs[c * 1024 + (wave << 8)]);
        }
        __syncthreads();
        #pragma unroll
        for (int kk = 0; kk < BK; kk++) {
            float a[8], bb[8];
            #pragma unroll
            for (int i = 0; i < 8; i++) a[i] = As[(ty * 8 + i) * 32 + kk];
            #pragma unroll
            for (int j = 0; j < 8; j++) bb[j] = Bs[kk * 128 + tx + j * 16];
            #pragma unroll
            for (int i = 0; i < 8; i++)
                #pragma unroll
                for (int j = 0; j < 8; j++) acc[i][j] += a[i] * bb[j];
        }
        __syncthreads();
    }

    #pragma unroll
    for (int i = 0; i < 8; i++) {
        int r = row0 + ty * 8 + i;
        #pragma unroll
        for (int j = 0; j < 8; j++) {
            int c = col0 + tx + j * 16;
            float v = acc[i][j];
            if (RES == 1) v += res[(size_t)r * N + c];
            if (OUTMODE == 0) {
                out[(size_t)r * N + c] = v;
            } else {
                int b = r >> 12, s = r & (S_ - 1);
                int h = c >> 6, kk2 = c & 63;
                out[((size_t)(b * H_ + h) * S_ + s) * 64 + kk2] = v;
            }
        }
    }
}

// ---------------------------------------------------------------------------
// bf16 MFMA GEMM (post-hash smooth path). A: [M,K] bf16 RM. Bt: [N,K] bf16.
// ---------------------------------------------------------------------------
template<int OUTMODE, int RES, bool BIAS, bool RELU>
__global__ __launch_bounds__(256) void mgemm_k(
    const short* __restrict__ A, const short* __restrict__ Bt,
    const float* __restrict__ bias, const float* __restrict__ res,
    void* __restrict__ out, int N, int K)
{
    __shared__ short As[128 * 32];
    __shared__ short Bs[128 * 32];

    int tid = threadIdx.x;
    int wave = tid >> 6, lane = tid & 63;
    int nbx = N >> 7;
    int bx = blockIdx.x % nbx, by = blockIdx.x / nbx;
    int row0 = by << 7, col0 = bx << 7;
    int wr = wave >> 1, wc = wave & 1;   // 64x64 wave tile
    int fr = lane & 15, fq = lane >> 4;

    facc acc[4][4];
    facc zero = {0.f, 0.f, 0.f, 0.f};
    #pragma unroll
    for (int m = 0; m < 4; m++)
        #pragma unroll
        for (int n = 0; n < 4; n++) acc[m][n] = zero;

    const short* gA = A + (size_t)(row0 + (wave << 5) + (lane >> 2)) * K + ((lane & 3) << 3);
    const short* gB = Bt + (size_t)(col0 + (wave << 5) + (lane >> 2)) * K + ((lane & 3) << 3);

    for (int k0 = 0; k0 < K; k0 += 32) {
        GLL(gA + k0,                 &As[wave << 10]);
        GLL(gA + k0 + (size_t)16 * K, &As[(wave << 10) + 512]);
        GLL(gB + k0,                 &Bs[wave << 10]);
        GLL(gB + k0 + (size_t)16 * K, &Bs[(wave << 10) + 512]);
        __syncthreads();

        bfrag av[4], bv[4];
        #pragma unroll
        for (int m = 0; m < 4; m++)
            av[m] = *reinterpret_cast<const bfrag*>(&As[(((wr << 6) + (m << 4) + fr) << 5) + (fq << 3)]);
        #pragma unroll
        for (int n = 0; n < 4; n++)
            bv[n] = *reinterpret_cast<const bfrag*>(&Bs[(((wc << 6) + (n << 4) + fr) << 5) + (fq << 3)]);
        #pragma unroll
        for (int m = 0; m < 4; m++)
            #pragma unroll
            for (int n = 0; n < 4; n++)
                acc[m][n] = __builtin_amdgcn_mfma_f32_16x16x32_bf16(av[m], bv[n], acc[m][n], 0, 0, 0);
        __syncthreads();
    }

    #pragma unroll
    for (int m = 0; m < 4; m++) {
        #pragma unroll
        for (int n = 0; n < 4; n++) {
            #pragma unroll
            for (int r = 0; r < 4; r++) {
                int row = row0 + (wr << 6) + (m << 4) + (fq << 2) + r;
                int col = col0 + (wc << 6) + (n << 4) + fr;
                float v = acc[m][n][r];
                if (BIAS) v += bias[col];
                if (RELU) v = fmaxf(v, 0.f);
                if (RES == 1) v += res[(size_t)row * N + col];
                if (OUTMODE == 0) {
                    ((float*)out)[(size_t)row * N + col] = v;
                } else if (OUTMODE == 1) {
                    ((bf16*)out)[(size_t)row * N + col] = __float2bfloat16(v);
                } else {
                    int b = row >> 12, s = row & (S_ - 1);
                    int h = col >> 6, kk2 = col & 63;
                    ((bf16*)out)[(((size_t)(b * H_ + h) * S_ + s) << 6) + kk2] = __float2bfloat16(v);
                }
            }
        }
    }
}

// ---------------------------------------------------------------------------
// Weight converters
// ---------------------------------------------------------------------------
__global__ __launch_bounds__(256) void convw_k(
    const float* __restrict__ W, bf16* __restrict__ Wt, int N, int K)
{
    int i = blockIdx.x * 256 + threadIdx.x;
    int n = i / K, k = i % K;
    Wt[i] = __float2bfloat16(W[(size_t)k * N + n]);
}

__global__ __launch_bounds__(256) void wrot_k(
    const float* __restrict__ W, const float* __restrict__ rot,
    float* __restrict__ wrot)
{
    int d = blockIdx.x, t = threadIdx.x;
    int h = t >> 5, j = t & 31;
    float a = 0.f;
    #pragma unroll
    for (int k = 0; k < 64; k++)
        a += W[(size_t)(d * H_ + h) * 64 + k] * rot[(size_t)(h * 64 + k) * 32 + j];
    wrot[(size_t)d * 256 + t] = a;
}

__global__ __launch_bounds__(256) void cast_k(
    const float* __restrict__ x, bf16* __restrict__ y)
{
    size_t i = ((size_t)blockIdx.x * 256 + threadIdx.x) * 4;
    float4 v = *reinterpret_cast<const float4*>(x + i);
    y[i]     = __float2bfloat16(v.x);
    y[i + 1] = __float2bfloat16(v.y);
    y[i + 2] = __float2bfloat16(v.z);
    y[i + 3] = __float2bfloat16(v.w);
}

// ---------------------------------------------------------------------------
// SA hash (from f32 q/k scatter layout)
// ---------------------------------------------------------------------------
__global__ __launch_bounds__(256) void hash_k(
    const float* __restrict__ t, const float* __restrict__ rot,
    int* __restrict__ bucket)
{
    int bh = blockIdx.x >> 4;
    int st = blockIdx.x & 15;
    int h = bh % H_;
    __shared__ float rs[64][32];
    int tid = threadIdx.x;
    for (int e = tid; e < 2048; e += 256)
        rs[e >> 5][e & 31] = rot[h * 2048 + e];
    __syncthreads();

    int s = st * 256 + tid;
    const float* qr = t + ((size_t)bh * S_ + s) * 64;
    float qv[64];
    #pragma unroll
    for (int i = 0; i < 64; i++) qv[i] = qr[i];
    float r[32];
    #pragma unroll
    for (int j = 0; j < 32; j++) {
        float a = 0.f;
        #pragma unroll
        for (int kk = 0; kk < 64; kk++) a += qv[kk] * rs[kk][j];
        r[j] = a;
    }
    float best = -INFINITY; int bi = 0;
    #pragma unroll
    for (int j = 0; j < 32; j++) { if (r[j] > best) { best = r[j]; bi = j; } }
    #pragma unroll
    for (int j = 0; j < 32; j++) { float v = -r[j]; if (v > best) { best = v; bi = 32 + j; } }
    bucket[(size_t)bh * S_ + s] = bi;
}

// ---------------------------------------------------------------------------
// CA hash argmax from projection r [M,256] (col = h*32+j).
// One thread per (row, h): strict-> scans = first-index tie-break, exactly
// argmax over concat([r,-r]).
// ---------------------------------------------------------------------------
__global__ __launch_bounds__(256) void amax_k(
    const float* __restrict__ r, int* __restrict__ bucket)
{
    int idx = blockIdx.x * 256 + threadIdx.x;
    int row = idx >> 3, h = idx & 7;
    const float* rr = r + (size_t)row * 256 + h * 32;
    float best = -INFINITY; int bi = 0;
    #pragma unroll
    for (int j = 0; j < 32; j++) { float v = rr[j]; if (v > best) { best = v; bi = j; } }
    #pragma unroll
    for (int j = 0; j < 32; j++) { float v = -rr[j]; if (v > best) { best = v; bi = 32 + j; } }
    int b = row >> 12, s = row & (S_ - 1);
    bucket[((size_t)(b * H_ + h)) * S_ + s] = bi;
}

// ---------------------------------------------------------------------------
// Stable counting sort by bucket per (b,h) — argsort(bucket*S + pos).
// ---------------------------------------------------------------------------
__global__ __launch_bounds__(64) void sort_k(
    const int* __restrict__ bucket, int* __restrict__ perm)
{
    int bh = blockIdx.x;
    __shared__ int lb[S_];
    int tid = threadIdx.x;
    for (int i = tid; i < S_; i += 64) lb[i] = bucket[(size_t)bh * S_ + i];
    __syncthreads();
    int cnt = 0;
    for (int i = 0; i < S_; i++) cnt += (lb[i] == tid) ? 1 : 0;
    int incl = cnt;
    #pragma unroll
    for (int off = 1; off < 64; off <<= 1) {
        int n = __shfl_up(incl, off, 64);
        if (tid >= off) incl += n;
    }
    int idx = incl - cnt;
    int* pr = perm + (size_t)bh * S_;
    for (int i = 0; i < S_; i++)
        if (lb[i] == tid) pr[idx++] = i;
}

// ---------------------------------------------------------------------------
// Chunked LSH attention: 4 waves/block, quad-per-query (round-5 structure).
// ---------------------------------------------------------------------------
template<typename T, typename OT>
__global__ __launch_bounds__(256, 4) void attn_k(
    const T* __restrict__ q, const T* __restrict__ k,
    const T* __restrict__ v, const int* __restrict__ bq,
    const int* __restrict__ bk, const int* __restrict__ permq,
    const int* __restrict__ permk, OT* __restrict__ o)
{
    int c = blockIdx.x % NC_;
    int bh = blockIdx.x / NC_;
    int b = bh / H_, h = bh % H_;
    __shared__ float kv[128][64];
    __shared__ int skx[128];
    __shared__ int bkx[128];
    int tid = threadIdx.x;
    const int qq = tid >> 2, u = tid & 3;
    const size_t bhS = (size_t)bh * S_;

    if (tid < 128) {
        int sidx = (tid < 64) ? (((c + NC_ - 1) & (NC_ - 1)) * 64 + tid)
                              : (c * 64 + (tid - 64));
        int sk = permk[bhS + sidx];
        skx[tid] = sk;
        bkx[tid] = bk[bhS + sk];
    }
    __syncthreads();

    {
        int rr = tid >> 4, c4 = (tid & 15) << 2;
        #pragma unroll
        for (int pass = 0; pass < 8; pass++) {
            int row = pass * 16 + rr;
            *reinterpret_cast<float4*>(&kv[row][c4]) =
                ld4g(k + (bhS + skx[row]) * 64 + c4);
        }
    }

    int sq = permq[bhS + c * 64 + qq];
    float4 qv[4];
    {
        const T* qr = q + (bhS + sq) * 64 + u * 16;
        #pragma unroll
        for (int i = 0; i < 4; i++) qv[i] = ld4g(qr + i * 4);
    }
    int bqi = bq[bhS + sq];
    __syncthreads();

    float p[32];
    #pragma unroll
    for (int g = 0; g < 4; g++) {
        float part[32];
        #pragma unroll
        for (int t = 0; t < 32; t++) {
            const float4* kr = reinterpret_cast<const float4*>(&kv[g * 32 + t][u << 4]);
            float4 k0 = kr[0], k1 = kr[1], k2 = kr[2], k3 = kr[3];
            float s0 = qv[0].x * k0.x + qv[0].y * k0.y + qv[0].z * k0.z + qv[0].w * k0.w;
            float s1 = qv[1].x * k1.x + qv[1].y * k1.y + qv[1].z * k1.z + qv[1].w * k1.w;
            float s2 = qv[2].x * k2.x + qv[2].y * k2.y + qv[2].z * k2.z + qv[2].w * k2.w;
            float s3 = qv[3].x * k3.x + qv[3].y * k3.y + qv[3].z * k3.z + qv[3].w * k3.w;
            part[t] = (s0 + s1) + (s2 + s3);
        }
        float keep[16];
        #pragma unroll
        for (int t = 0; t < 16; t++) {
            float lo = __shfl_xor(part[t], 2, 64);
            float hi = __shfl_xor(part[16 + t], 2, 64);
            keep[t] = (u < 2) ? part[t] + lo : part[16 + t] + hi;
        }
        #pragma unroll
        for (int t = 0; t < 8; t++) {
            float lo = __shfl_xor(keep[t], 1, 64);
            float hi = __shfl_xor(keep[8 + t], 1, 64);
            float s = ((u & 1) == 0) ? keep[t] + lo : keep[8 + t] + hi;
            int j = g * 32 + (u >> 1) * 16 + (u & 1) * 8 + t;
            p[g * 8 + t] = (bqi == bkx[j]) ? s * 0.125f : -1e9f;
        }
    }

    float m = -INFINITY;
    #pragma unroll
    for (int i = 0; i < 32; i++) m = fmaxf(m, p[i]);
    m = fmaxf(m, __shfl_xor(m, 1, 64));
    m = fmaxf(m, __shfl_xor(m, 2, 64));
    float l = 0.f;
    #pragma unroll
    for (int i = 0; i < 32; i++) { p[i] = __expf(p[i] - m); l += p[i]; }
    l += __shfl_xor(l, 1, 64);
    l += __shfl_xor(l, 2, 64);

    __syncthreads();
    {
        int rr = tid >> 4, c4 = (tid & 15) << 2;
        #pragma unroll
        for (int pass = 0; pass < 8; pass++) {
            int row = pass * 16 + rr;
            *reinterpret_cast<float4*>(&kv[row][c4]) =
                ld4g(v + (bhS + skx[row]) * 64 + c4);
        }
    }
    __syncthreads();

    float4 acc0 = make_float4(0.f, 0.f, 0.f, 0.f);
    float4 acc1 = make_float4(0.f, 0.f, 0.f, 0.f);
    float4 acc2 = make_float4(0.f, 0.f, 0.f, 0.f);
    float4 acc3 = make_float4(0.f, 0.f, 0.f, 0.f);
    int base = tid & ~3;
    #pragma unroll
    for (int j = 0; j < 128; j++) {
        const int uo = ((j >> 3) & 1) | (((j >> 4) & 1) << 1);
        const int slot = ((j >> 5) << 3) | (j & 7);
        float pj = __shfl(p[slot], base + uo, 64);
        const float4* vr = reinterpret_cast<const float4*>(&kv[j][u << 4]);
        float4 v0 = vr[0], v1 = vr[1], v2 = vr[2], v3 = vr[3];
        acc0.x += pj * v0.x; acc0.y += pj * v0.y; acc0.z += pj * v0.z; acc0.w += pj * v0.w;
        acc1.x += pj * v1.x; acc1.y += pj * v1.y; acc1.z += pj * v1.z; acc1.w += pj * v1.w;
        acc2.x += pj * v2.x; acc2.y += pj * v2.y; acc2.z += pj * v2.z; acc2.w += pj * v2.w;
        acc3.x += pj * v3.x; acc3.y += pj * v3.y; acc3.z += pj * v3.z; acc3.w += pj * v3.w;
    }
    float inv = 1.0f / l;
    OT* orow = o + ((size_t)b * S_ + sq) * 512 + h * 64 + (u << 4);
    st4(orow + 0,  make_float4(acc0.x * inv, acc0.y * inv, acc0.z * inv, acc0.w * inv));
    st4(orow + 4,  make_float4(acc1.x * inv, acc1.y * inv, acc1.z * inv, acc1.w * inv));
    st4(orow + 8,  make_float4(acc2.x * inv, acc2.y * inv, acc2.z * inv, acc2.w * inv));
    st4(orow + 12, make_float4(acc3.x * inv, acc3.y * inv, acc3.z * inv, acc3.w * inv));
}

// ---------------------------------------------------------------------------
// LayerNorm per row of [M,512], f32 out (+ optional bf16 copy).
// ---------------------------------------------------------------------------
template<bool BFC>
__global__ __launch_bounds__(256) void ln_k(
    const float* __restrict__ x, const float* __restrict__ g,
    const float* __restrict__ bvec, float* __restrict__ out,
    bf16* __restrict__ bfout)
{
    int row = blockIdx.x;
    int tid = threadIdx.x;
    __shared__ float red[256];
    const float* xr = x + (size_t)row * D_;
    float v0 = xr[tid], v1 = xr[tid + 256];
    red[tid] = v0 + v1;
    __syncthreads();
    for (int off = 128; off > 0; off >>= 1) {
        if (tid < off) red[tid] += red[tid + off];
        __syncthreads();
    }
    float mean = red[0] / 512.f;
    __syncthreads();
    float d0 = v0 - mean, d1 = v1 - mean;
    red[tid] = d0 * d0 + d1 * d1;
    __syncthreads();
    for (int off = 128; off > 0; off >>= 1) {
        if (tid < off) red[tid] += red[tid + off];
        __syncthreads();
    }
    float var = red[0] / 512.f;
    float rs = 1.0f / sqrtf(var + 1e-5f);
    float y0 = d0 * rs * g[tid] + bvec[tid];
    float y1 = d1 * rs * g[tid + 256] + bvec[tid + 256];
    out[(size_t)row * D_ + tid] = y0;
    out[(size_t)row * D_ + tid + 256] = y1;
    if (BFC) {
        bfout[(size_t)row * D_ + tid] = __float2bfloat16(y0);
        bfout[(size_t)row * D_ + tid + 256] = __float2bfloat16(y1);
    }
}

// ---------------------------------------------------------------------------
extern "C" void kernel_launch(void* const* d_in, const int* in_sizes, int n_in,
                              void* d_out, int out_size, void* d_ws, size_t ws_size,
                              hipStream_t stream)
{
    (void)in_sizes; (void)n_in; (void)out_size; (void)ws_size;
    const float* dec   = (const float*)d_in[0];
    const float* enc   = (const float*)d_in[1];
    const float* sa_Wq = (const float*)d_in[2];
    const float* sa_Wk = (const float*)d_in[3];
    const float* sa_Wv = (const float*)d_in[4];
    const float* sa_Wo = (const float*)d_in[5];
    const float* sa_g  = (const float*)d_in[6];
    const float* sa_b  = (const float*)d_in[7];
    const float* sa_rot= (const float*)d_in[8];
    const float* ca_Wq = (const float*)d_in[9];
    const float* ca_Wk = (const float*)d_in[10];
    const float* ca_Wv = (const float*)d_in[11];
    const float* ca_Wo = (const float*)d_in[12];
    const float* ca_g  = (const float*)d_in[13];
    const float* ca_b  = (const float*)d_in[14];
    const float* ca_rot= (const float*)d_in[15];
    const float* ff_W1 = (const float*)d_in[16];
    const float* ff_b1 = (const float*)d_in[17];
    const float* ff_W2 = (const float*)d_in[18];
    const float* ff_b2 = (const float*)d_in[19];
    const float* ff_g  = (const float*)d_in[20];
    const float* ff_b  = (const float*)d_in[21];

    char* ws = (char*)d_ws;
    const size_t MB = 1ull << 20;
    // SA phase (f32)
    float* qb     = (float*)(ws + 0);        // 32MB
    float* kb     = (float*)(ws + 32*MB);    // 32MB
    float* vb     = (float*)(ws + 64*MB);    // 32MB
    float* ob     = (float*)(ws + 96*MB);    // 32MB
    float* act0   = (float*)(ws + 128*MB);   // 32MB (live thru ca_Wo residual)
    bf16*  act0bf = (bf16*)(ws + 160*MB);    // 16MB
    // CA hash projections (overlay dead qb/kb region, consumed before cq/ck)
    float* rq     = (float*)(ws + 0);        // 16.8MB
    float* rk     = (float*)(ws + 17*MB);    // 16.8MB
    // CA phase overlays
    bf16*  cq     = (bf16*)(ws + 0);         // 16MB
    bf16*  ck     = (bf16*)(ws + 16*MB);     // 16MB
    bf16*  cv     = (bf16*)(ws + 32*MB);     // 16MB
    bf16*  caOut  = (bf16*)(ws + 48*MB);     // 16MB
    bf16*  encbf  = (bf16*)(ws + 64*MB);     // 16MB
    bf16*  act1bf = (bf16*)(ws + 80*MB);     // 16MB
    float* act1   = (float*)(ws + 96*MB);    // 32MB
    // FF overlays (cq..caOut dead)
    bf16*  hid    = (bf16*)(ws + 0);         // 64MB
    float* ffout  = (float*)(ws + 128*MB);   // 32MB (act0 dead)
    // weights / hash
    bf16*  caWqt  = (bf16*)(ws + 176*MB);
    bf16*  caWkt  = (bf16*)(ws + 176*MB + 512*1024);
    bf16*  caWvt  = (bf16*)(ws + 177*MB);
    bf16*  caWot  = (bf16*)(ws + 177*MB + 512*1024);
    bf16*  ffW1t  = (bf16*)(ws + 178*MB);    // 2MB
    bf16*  ffW2t  = (bf16*)(ws + 180*MB);    // 2MB
    float* wrotq  = (float*)(ws + 182*MB);
    float* wrotk  = (float*)(ws + 182*MB + 512*1024);
    int*   bqb    = (int*)(ws + 183*MB);
    int*   bkb    = (int*)(ws + 183*MB + 512*1024);
    int*   pqb    = (int*)(ws + 184*MB);
    int*   pkb    = (int*)(ws + 184*MB + 512*1024);   // ends at 185MB

    dim3 blk(256);
    const int g512  = (M_ / 128) * (512 / 128);    // 512 blocks
    const int g256  = (M_ / 128) * (256 / 128);    // 256 blocks (proj)
    const int g2048 = (M_ / 128) * (2048 / 128);   // 2048 blocks

    // ---- converters (independent) ----
    wrot_k<<<512, blk, 0, stream>>>(ca_Wq, ca_rot, wrotq);
    wrot_k<<<512, blk, 0, stream>>>(ca_Wk, ca_rot, wrotk);
    convw_k<<<1024, blk, 0, stream>>>(ca_Wq, caWqt, 512, 512);
    convw_k<<<1024, blk, 0, stream>>>(ca_Wk, caWkt, 512, 512);
    convw_k<<<1024, blk, 0, stream>>>(ca_Wv, caWvt, 512, 512);
    convw_k<<<1024, blk, 0, stream>>>(ca_Wo, caWot, 512, 512);
    convw_k<<<4096, blk, 0, stream>>>(ff_W1, ffW1t, 2048, 512);
    convw_k<<<4096, blk, 0, stream>>>(ff_W2, ffW2t, 512, 2048);

    // ---------------- self-attention (f32-class, feeds ca-hash) ----------
    gemm_k<1,0><<<g512, blk, 0, stream>>>(dec, sa_Wq, nullptr, qb, 512, 512);
    gemm_k<1,0><<<g512, blk, 0, stream>>>(dec, sa_Wk, nullptr, kb, 512, 512);
    gemm_k<1,0><<<g512, blk, 0, stream>>>(dec, sa_Wv, nullptr, vb, 512, 512);
    hash_k<<<BH_ * 16, blk, 0, stream>>>(qb, sa_rot, bqb);
    hash_k<<<BH_ * 16, blk, 0, stream>>>(kb, sa_rot, bkb);
    sort_k<<<BH_, dim3(64), 0, stream>>>(bqb, pqb);
    sort_k<<<BH_, dim3(64), 0, stream>>>(bkb, pkb);
    attn_k<float,float><<<BH_ * NC_, blk, 0, stream>>>(qb, kb, vb, bqb, bkb, pqb, pkb, ob);
    gemm_k<0,1><<<g512, blk, 0, stream>>>(ob, sa_Wo, dec, act0, 512, 512);
    ln_k<true><<<M_, blk, 0, stream>>>(act0, sa_g, sa_b, act0, act0bf);

    // ---------------- cross-attention ----------------
    // hash projections as tiled GEMMs (r = x @ wrot), then argmax
    gemm_k<0,0><<<g256, blk, 0, stream>>>(act0, wrotq, nullptr, rq, 256, 512);
    gemm_k<0,0><<<g256, blk, 0, stream>>>(enc,  wrotk, nullptr, rk, 256, 512);
    amax_k<<<M_ * 8 / 256, blk, 0, stream>>>(rq, bqb);
    amax_k<<<M_ * 8 / 256, blk, 0, stream>>>(rk, bkb);
    sort_k<<<BH_, dim3(64), 0, stream>>>(bqb, pqb);
    sort_k<<<BH_, dim3(64), 0, stream>>>(bkb, pkb);
    cast_k<<<M_ * 512 / 1024, blk, 0, stream>>>(enc, encbf);
    mgemm_k<2,0,false,false><<<g512, blk, 0, stream>>>((const short*)act0bf, (const short*)caWqt, nullptr, nullptr, cq, 512, 512);
    mgemm_k<2,0,false,false><<<g512, blk, 0, stream>>>((const short*)encbf, (const short*)caWkt, nullptr, nullptr, ck, 512, 512);
    mgemm_k<2,0,false,false><<<g512, blk, 0, stream>>>((const short*)encbf, (const short*)caWvt, nullptr, nullptr, cv, 512, 512);
    attn_k<bf16,bf16><<<BH_ * NC_, blk, 0, stream>>>(cq, ck, cv, bqb, bkb, pqb, pkb, caOut);
    mgemm_k<0,1,false,false><<<g512, blk, 0, stream>>>((const short*)caOut, (const short*)caWot, nullptr, act0, act1, 512, 512);
    ln_k<true><<<M_, blk, 0, stream>>>(act1, ca_g, ca_b, act1, act1bf);

    // ---------------- feed-forward ----------------
    mgemm_k<1,0,true,true><<<g2048, blk, 0, stream>>>((const short*)act1bf, (const short*)ffW1t, ff_b1, nullptr, hid, 2048, 512);
    mgemm_k<0,1,true,false><<<g512, blk, 0, stream>>>((const short*)hid, (const short*)ffW2t, ff_b2, act1, ffout, 512, 2048);
    ln_k<false><<<M_, blk, 0, stream>>>(ffout, ff_g, ff_b, (float*)d_out, nullptr);
}

// Round 7
// 1240.935 us; speedup vs baseline: 3.5964x; 1.8796x over previous
//
#include <hip/hip_runtime.h>
#include <hip/hip_bf16.h>
#include <math.h>

typedef __hip_bfloat16 bf16;

#define B_ 4
#define S_ 4096
#define D_ 512
#define H_ 8
#define NC_ 64
#define M_ (B_*S_)     // 16384
#define BH_ (B_*H_)    // 32

typedef __attribute__((ext_vector_type(8))) short bfrag;   // 8 bf16 (4 VGPRs)
typedef __attribute__((ext_vector_type(4))) float facc;    // 4 f32 acc

static __device__ __forceinline__ float tof(float x){ return x; }
static __device__ __forceinline__ float tof(bf16 x){ return __bfloat162float(x); }

static __device__ __forceinline__ float4 ld4g(const float* p) {
    return *reinterpret_cast<const float4*>(p);
}
static __device__ __forceinline__ float4 ld4g(const bf16* p) {
    short4 s = *reinterpret_cast<const short4*>(p);
    float4 r;
    r.x = __bfloat162float(*reinterpret_cast<const bf16*>(&s.x));
    r.y = __bfloat162float(*reinterpret_cast<const bf16*>(&s.y));
    r.z = __bfloat162float(*reinterpret_cast<const bf16*>(&s.z));
    r.w = __bfloat162float(*reinterpret_cast<const bf16*>(&s.w));
    return r;
}
static __device__ __forceinline__ void st4(float* p, float4 v) {
    *reinterpret_cast<float4*>(p) = v;
}
static __device__ __forceinline__ void st4(bf16* p, float4 v) {
    bf16 b0 = __float2bfloat16(v.x), b1 = __float2bfloat16(v.y);
    bf16 b2 = __float2bfloat16(v.z), b3 = __float2bfloat16(v.w);
    short4 s;
    s.x = *reinterpret_cast<short*>(&b0);
    s.y = *reinterpret_cast<short*>(&b1);
    s.z = *reinterpret_cast<short*>(&b2);
    s.w = *reinterpret_cast<short*>(&b3);
    *reinterpret_cast<short4*>(p) = s;
}

#define GLL(gp, lp) __builtin_amdgcn_global_load_lds( \
    (const __attribute__((address_space(1))) void*)(gp), \
    (__attribute__((address_space(3))) void*)(lp), 16, 0, 0)

// ---------------------------------------------------------------------------
// f32 VALU GEMM (hash-feeding paths; f32-class accuracy required).
// BK=32, global_load_lds staging. OUTMODE: 0 = f32 RM, 1 = qkv-scatter.
// RES: 0 = none, 1 = f32 residual row-major [M,N]
// ---------------------------------------------------------------------------
template<int OUTMODE, int RES>
__global__ __launch_bounds__(256) void gemm_k(
    const float* __restrict__ A, const float* __restrict__ Bw,
    const float* __restrict__ res, float* __restrict__ out, int N, int K)
{
    const int BK = 32;
    __shared__ float As[128 * 32];   // [row][k] row-major
    __shared__ float Bs[32 * 128];   // [k][col] row-major

    int tid = threadIdx.x;
    int wave = tid >> 6;
    int nbx = N >> 7;
    int bx = blockIdx.x % nbx;
    int by = blockIdx.x / nbx;
    int row0 = by << 7;
    int col0 = bx << 7;
    int ty = tid >> 4;   // 0..15
    int tx = tid & 15;   // 0..15

    float acc[8][8];
    #pragma unroll
    for (int i = 0; i < 8; i++)
        #pragma unroll
        for (int j = 0; j < 8; j++) acc[i][j] = 0.f;

    for (int k0 = 0; k0 < K; k0 += BK) {
        #pragma unroll
        for (int c = 0; c < 4; c++) {
            int e = c * 256 + tid;
            GLL(A + (size_t)(row0 + (e >> 3)) * K + k0 + ((e & 7) << 2),
                &As[c * 1024 + (wave << 8)]);
        }
        #pragma unroll
        for (int c = 0; c < 4; c++) {
            int e = c * 256 + tid;
            GLL(Bw + (size_t)(k0 + (e >> 5)) * N + col0 + ((e & 31) << 2),
                &Bs[c * 1024 + (wave << 8)]);
        }
        __syncthreads();
        #pragma unroll
        for (int kk = 0; kk < BK; kk++) {
            float a[8], bb[8];
            #pragma unroll
            for (int i = 0; i < 8; i++) a[i] = As[(ty * 8 + i) * 32 + kk];
            #pragma unroll
            for (int j = 0; j < 8; j++) bb[j] = Bs[kk * 128 + tx + j * 16];
            #pragma unroll
            for (int i = 0; i < 8; i++)
                #pragma unroll
                for (int j = 0; j < 8; j++) acc[i][j] += a[i] * bb[j];
        }
        __syncthreads();
    }

    #pragma unroll
    for (int i = 0; i < 8; i++) {
        int r = row0 + ty * 8 + i;
        #pragma unroll
        for (int j = 0; j < 8; j++) {
            int c = col0 + tx + j * 16;
            float v = acc[i][j];
            if (RES == 1) v += res[(size_t)r * N + c];
            if (OUTMODE == 0) {
                out[(size_t)r * N + c] = v;
            } else {
                int b = r >> 12, s = r & (S_ - 1);
                int h = c >> 6, kk2 = c & 63;
                out[((size_t)(b * H_ + h) * S_ + s) * 64 + kk2] = v;
            }
        }
    }
}

// ---------------------------------------------------------------------------
// bf16 MFMA GEMM (post-hash smooth path). A: [M,K] bf16 RM. Bt: [N,K] bf16.
// ---------------------------------------------------------------------------
template<int OUTMODE, int RES, bool BIAS, bool RELU>
__global__ __launch_bounds__(256) void mgemm_k(
    const short* __restrict__ A, const short* __restrict__ Bt,
    const float* __restrict__ bias, const float* __restrict__ res,
    void* __restrict__ out, int N, int K)
{
    __shared__ short As[128 * 32];
    __shared__ short Bs[128 * 32];

    int tid = threadIdx.x;
    int wave = tid >> 6, lane = tid & 63;
    int nbx = N >> 7;
    int bx = blockIdx.x % nbx, by = blockIdx.x / nbx;
    int row0 = by << 7, col0 = bx << 7;
    int wr = wave >> 1, wc = wave & 1;   // 64x64 wave tile
    int fr = lane & 15, fq = lane >> 4;

    facc acc[4][4];
    facc zero = {0.f, 0.f, 0.f, 0.f};
    #pragma unroll
    for (int m = 0; m < 4; m++)
        #pragma unroll
        for (int n = 0; n < 4; n++) acc[m][n] = zero;

    const short* gA = A + (size_t)(row0 + (wave << 5) + (lane >> 2)) * K + ((lane & 3) << 3);
    const short* gB = Bt + (size_t)(col0 + (wave << 5) + (lane >> 2)) * K + ((lane & 3) << 3);

    for (int k0 = 0; k0 < K; k0 += 32) {
        GLL(gA + k0,                 &As[wave << 10]);
        GLL(gA + k0 + (size_t)16 * K, &As[(wave << 10) + 512]);
        GLL(gB + k0,                 &Bs[wave << 10]);
        GLL(gB + k0 + (size_t)16 * K, &Bs[(wave << 10) + 512]);
        __syncthreads();

        bfrag av[4], bv[4];
        #pragma unroll
        for (int m = 0; m < 4; m++)
            av[m] = *reinterpret_cast<const bfrag*>(&As[(((wr << 6) + (m << 4) + fr) << 5) + (fq << 3)]);
        #pragma unroll
        for (int n = 0; n < 4; n++)
            bv[n] = *reinterpret_cast<const bfrag*>(&Bs[(((wc << 6) + (n << 4) + fr) << 5) + (fq << 3)]);
        #pragma unroll
        for (int m = 0; m < 4; m++)
            #pragma unroll
            for (int n = 0; n < 4; n++)
                acc[m][n] = __builtin_amdgcn_mfma_f32_16x16x32_bf16(av[m], bv[n], acc[m][n], 0, 0, 0);
        __syncthreads();
    }

    #pragma unroll
    for (int m = 0; m < 4; m++) {
        #pragma unroll
        for (int n = 0; n < 4; n++) {
            #pragma unroll
            for (int r = 0; r < 4; r++) {
                int row = row0 + (wr << 6) + (m << 4) + (fq << 2) + r;
                int col = col0 + (wc << 6) + (n << 4) + fr;
                float v = acc[m][n][r];
                if (BIAS) v += bias[col];
                if (RELU) v = fmaxf(v, 0.f);
                if (RES == 1) v += res[(size_t)row * N + col];
                if (OUTMODE == 0) {
                    ((float*)out)[(size_t)row * N + col] = v;
                } else if (OUTMODE == 1) {
                    ((bf16*)out)[(size_t)row * N + col] = __float2bfloat16(v);
                } else {
                    int b = row >> 12, s = row & (S_ - 1);
                    int h = col >> 6, kk2 = col & 63;
                    ((bf16*)out)[(((size_t)(b * H_ + h) * S_ + s) << 6) + kk2] = __float2bfloat16(v);
                }
            }
        }
    }
}

// ---------------------------------------------------------------------------
// Weight converters
// ---------------------------------------------------------------------------
__global__ __launch_bounds__(256) void convw_k(
    const float* __restrict__ W, bf16* __restrict__ Wt, int N, int K)
{
    int i = blockIdx.x * 256 + threadIdx.x;
    int n = i / K, k = i % K;
    Wt[i] = __float2bfloat16(W[(size_t)k * N + n]);
}

__global__ __launch_bounds__(256) void wrot_k(
    const float* __restrict__ W, const float* __restrict__ rot,
    float* __restrict__ wrot)
{
    int d = blockIdx.x, t = threadIdx.x;
    int h = t >> 5, j = t & 31;
    float a = 0.f;
    #pragma unroll
    for (int k = 0; k < 64; k++)
        a += W[(size_t)(d * H_ + h) * 64 + k] * rot[(size_t)(h * 64 + k) * 32 + j];
    wrot[(size_t)d * 256 + t] = a;
}

__global__ __launch_bounds__(256) void cast_k(
    const float* __restrict__ x, bf16* __restrict__ y)
{
    size_t i = ((size_t)blockIdx.x * 256 + threadIdx.x) * 4;
    float4 v = *reinterpret_cast<const float4*>(x + i);
    y[i]     = __float2bfloat16(v.x);
    y[i + 1] = __float2bfloat16(v.y);
    y[i + 2] = __float2bfloat16(v.z);
    y[i + 3] = __float2bfloat16(v.w);
}

// ---------------------------------------------------------------------------
// SA hash (from f32 q/k scatter layout)
// ---------------------------------------------------------------------------
__global__ __launch_bounds__(256) void hash_k(
    const float* __restrict__ t, const float* __restrict__ rot,
    int* __restrict__ bucket)
{
    int bh = blockIdx.x >> 4;
    int st = blockIdx.x & 15;
    int h = bh % H_;
    __shared__ float rs[64][32];
    int tid = threadIdx.x;
    for (int e = tid; e < 2048; e += 256)
        rs[e >> 5][e & 31] = rot[h * 2048 + e];
    __syncthreads();

    int s = st * 256 + tid;
    const float* qr = t + ((size_t)bh * S_ + s) * 64;
    float qv[64];
    #pragma unroll
    for (int i = 0; i < 64; i++) qv[i] = qr[i];
    float r[32];
    #pragma unroll
    for (int j = 0; j < 32; j++) {
        float a = 0.f;
        #pragma unroll
        for (int kk = 0; kk < 64; kk++) a += qv[kk] * rs[kk][j];
        r[j] = a;
    }
    float best = -INFINITY; int bi = 0;
    #pragma unroll
    for (int j = 0; j < 32; j++) { if (r[j] > best) { best = r[j]; bi = j; } }
    #pragma unroll
    for (int j = 0; j < 32; j++) { float v = -r[j]; if (v > best) { best = v; bi = 32 + j; } }
    bucket[(size_t)bh * S_ + s] = bi;
}

// ---------------------------------------------------------------------------
// CA hash argmax from projection r [M,256] (col = h*32+j).
// ---------------------------------------------------------------------------
__global__ __launch_bounds__(256) void amax_k(
    const float* __restrict__ r, int* __restrict__ bucket)
{
    int idx = blockIdx.x * 256 + threadIdx.x;
    int row = idx >> 3, h = idx & 7;
    const float* rr = r + (size_t)row * 256 + h * 32;
    float best = -INFINITY; int bi = 0;
    #pragma unroll
    for (int j = 0; j < 32; j++) { float v = rr[j]; if (v > best) { best = v; bi = j; } }
    #pragma unroll
    for (int j = 0; j < 32; j++) { float v = -rr[j]; if (v > best) { best = v; bi = 32 + j; } }
    int b = row >> 12, s = row & (S_ - 1);
    bucket[((size_t)(b * H_ + h)) * S_ + s] = bi;
}

// ---------------------------------------------------------------------------
// Parallel stable counting sort per (b,h) — exact argsort(bucket*S + pos).
// 256 threads; 128 segments x 32 elems. cnt[b][s] private column per thread
// (bank = s mod 32, conflict-free). Flat bucket-major exclusive prefix sum
// (= rank base), then in-order scatter per segment preserves stability.
// LDS: 16KB (lb) + 32KB (cnt) = 48KB.
// ---------------------------------------------------------------------------
__global__ __launch_bounds__(256) void sort_k(
    const int* __restrict__ bucket, int* __restrict__ perm)
{
    int bh = blockIdx.x;
    __shared__ int lb[S_];          // 16 KB
    __shared__ int cnt[64 * 128];   // 32 KB  cnt[b*128 + s]
    __shared__ int wtot[4];
    int tid = threadIdx.x;

    for (int i = tid; i < S_; i += 256) lb[i] = bucket[(size_t)bh * S_ + i];
    for (int i = tid; i < 8192; i += 256) cnt[i] = 0;
    __syncthreads();

    // histogram: segment s = tid (<128), column-private
    if (tid < 128) {
        int s0 = tid << 5;
        #pragma unroll
        for (int i = 0; i < 32; i++)
            cnt[(lb[s0 + i] << 7) + tid]++;
    }
    __syncthreads();

    // flat exclusive prefix over cnt[0..8191] (bucket-major = rank order)
    int base = tid << 5;
    int tsum = 0;
    #pragma unroll
    for (int i = 0; i < 32; i++) tsum += cnt[base + i];
    int incl = tsum;
    #pragma unroll
    for (int off = 1; off < 64; off <<= 1) {
        int n = __shfl_up(incl, off, 64);
        if ((tid & 63) >= off) incl += n;
    }
    if ((tid & 63) == 63) wtot[tid >> 6] = incl;
    __syncthreads();
    int wbase = 0;
    for (int w = 0; w < (tid >> 6); w++) wbase += wtot[w];
    int run = wbase + incl - tsum;
    #pragma unroll
    for (int i = 0; i < 32; i++) {
        int c = cnt[base + i];
        cnt[base + i] = run;
        run += c;
    }
    __syncthreads();

    // in-order scatter
    if (tid < 128) {
        int s0 = tid << 5;
        int* pr = perm + (size_t)bh * S_;
        #pragma unroll
        for (int i = 0; i < 32; i++) {
            int b = lb[s0 + i];
            int pos = cnt[(b << 7) + tid]++;
            pr[pos] = s0 + i;
        }
    }
}

// ---------------------------------------------------------------------------
// Chunked LSH attention: 4 waves/block, quad-per-query (round-5 structure).
// ---------------------------------------------------------------------------
template<typename T, typename OT>
__global__ __launch_bounds__(256, 4) void attn_k(
    const T* __restrict__ q, const T* __restrict__ k,
    const T* __restrict__ v, const int* __restrict__ bq,
    const int* __restrict__ bk, const int* __restrict__ permq,
    const int* __restrict__ permk, OT* __restrict__ o)
{
    int c = blockIdx.x % NC_;
    int bh = blockIdx.x / NC_;
    int b = bh / H_, h = bh % H_;
    __shared__ float kv[128][64];
    __shared__ int skx[128];
    __shared__ int bkx[128];
    int tid = threadIdx.x;
    const int qq = tid >> 2, u = tid & 3;
    const size_t bhS = (size_t)bh * S_;

    if (tid < 128) {
        int sidx = (tid < 64) ? (((c + NC_ - 1) & (NC_ - 1)) * 64 + tid)
                              : (c * 64 + (tid - 64));
        int sk = permk[bhS + sidx];
        skx[tid] = sk;
        bkx[tid] = bk[bhS + sk];
    }
    __syncthreads();

    {
        int rr = tid >> 4, c4 = (tid & 15) << 2;
        #pragma unroll
        for (int pass = 0; pass < 8; pass++) {
            int row = pass * 16 + rr;
            *reinterpret_cast<float4*>(&kv[row][c4]) =
                ld4g(k + (bhS + skx[row]) * 64 + c4);
        }
    }

    int sq = permq[bhS + c * 64 + qq];
    float4 qv[4];
    {
        const T* qr = q + (bhS + sq) * 64 + u * 16;
        #pragma unroll
        for (int i = 0; i < 4; i++) qv[i] = ld4g(qr + i * 4);
    }
    int bqi = bq[bhS + sq];
    __syncthreads();

    float p[32];
    #pragma unroll
    for (int g = 0; g < 4; g++) {
        float part[32];
        #pragma unroll
        for (int t = 0; t < 32; t++) {
            const float4* kr = reinterpret_cast<const float4*>(&kv[g * 32 + t][u << 4]);
            float4 k0 = kr[0], k1 = kr[1], k2 = kr[2], k3 = kr[3];
            float s0 = qv[0].x * k0.x + qv[0].y * k0.y + qv[0].z * k0.z + qv[0].w * k0.w;
            float s1 = qv[1].x * k1.x + qv[1].y * k1.y + qv[1].z * k1.z + qv[1].w * k1.w;
            float s2 = qv[2].x * k2.x + qv[2].y * k2.y + qv[2].z * k2.z + qv[2].w * k2.w;
            float s3 = qv[3].x * k3.x + qv[3].y * k3.y + qv[3].z * k3.z + qv[3].w * k3.w;
            part[t] = (s0 + s1) + (s2 + s3);
        }
        float keep[16];
        #pragma unroll
        for (int t = 0; t < 16; t++) {
            float lo = __shfl_xor(part[t], 2, 64);
            float hi = __shfl_xor(part[16 + t], 2, 64);
            keep[t] = (u < 2) ? part[t] + lo : part[16 + t] + hi;
        }
        #pragma unroll
        for (int t = 0; t < 8; t++) {
            float lo = __shfl_xor(keep[t], 1, 64);
            float hi = __shfl_xor(keep[8 + t], 1, 64);
            float s = ((u & 1) == 0) ? keep[t] + lo : keep[8 + t] + hi;
            int j = g * 32 + (u >> 1) * 16 + (u & 1) * 8 + t;
            p[g * 8 + t] = (bqi == bkx[j]) ? s * 0.125f : -1e9f;
        }
    }

    float m = -INFINITY;
    #pragma unroll
    for (int i = 0; i < 32; i++) m = fmaxf(m, p[i]);
    m = fmaxf(m, __shfl_xor(m, 1, 64));
    m = fmaxf(m, __shfl_xor(m, 2, 64));
    float l = 0.f;
    #pragma unroll
    for (int i = 0; i < 32; i++) { p[i] = __expf(p[i] - m); l += p[i]; }
    l += __shfl_xor(l, 1, 64);
    l += __shfl_xor(l, 2, 64);

    __syncthreads();
    {
        int rr = tid >> 4, c4 = (tid & 15) << 2;
        #pragma unroll
        for (int pass = 0; pass < 8; pass++) {
            int row = pass * 16 + rr;
            *reinterpret_cast<float4*>(&kv[row][c4]) =
                ld4g(v + (bhS + skx[row]) * 64 + c4);
        }
    }
    __syncthreads();

    float4 acc0 = make_float4(0.f, 0.f, 0.f, 0.f);
    float4 acc1 = make_float4(0.f, 0.f, 0.f, 0.f);
    float4 acc2 = make_float4(0.f, 0.f, 0.f, 0.f);
    float4 acc3 = make_float4(0.f, 0.f, 0.f, 0.f);
    int base = tid & ~3;
    #pragma unroll
    for (int j = 0; j < 128; j++) {
        const int uo = ((j >> 3) & 1) | (((j >> 4) & 1) << 1);
        const int slot = ((j >> 5) << 3) | (j & 7);
        float pj = __shfl(p[slot], base + uo, 64);
        const float4* vr = reinterpret_cast<const float4*>(&kv[j][u << 4]);
        float4 v0 = vr[0], v1 = vr[1], v2 = vr[2], v3 = vr[3];
        acc0.x += pj * v0.x; acc0.y += pj * v0.y; acc0.z += pj * v0.z; acc0.w += pj * v0.w;
        acc1.x += pj * v1.x; acc1.y += pj * v1.y; acc1.z += pj * v1.z; acc1.w += pj * v1.w;
        acc2.x += pj * v2.x; acc2.y += pj * v2.y; acc2.z += pj * v2.z; acc2.w += pj * v2.w;
        acc3.x += pj * v3.x; acc3.y += pj * v3.y; acc3.z += pj * v3.z; acc3.w += pj * v3.w;
    }
    float inv = 1.0f / l;
    OT* orow = o + ((size_t)b * S_ + sq) * 512 + h * 64 + (u << 4);
    st4(orow + 0,  make_float4(acc0.x * inv, acc0.y * inv, acc0.z * inv, acc0.w * inv));
    st4(orow + 4,  make_float4(acc1.x * inv, acc1.y * inv, acc1.z * inv, acc1.w * inv));
    st4(orow + 8,  make_float4(acc2.x * inv, acc2.y * inv, acc2.z * inv, acc2.w * inv));
    st4(orow + 12, make_float4(acc3.x * inv, acc3.y * inv, acc3.z * inv, acc3.w * inv));
}

// ---------------------------------------------------------------------------
// LayerNorm per row of [M,512], f32 out (+ optional bf16 copy).
// ---------------------------------------------------------------------------
template<bool BFC>
__global__ __launch_bounds__(256) void ln_k(
    const float* __restrict__ x, const float* __restrict__ g,
    const float* __restrict__ bvec, float* __restrict__ out,
    bf16* __restrict__ bfout)
{
    int row = blockIdx.x;
    int tid = threadIdx.x;
    __shared__ float red[256];
    const float* xr = x + (size_t)row * D_;
    float v0 = xr[tid], v1 = xr[tid + 256];
    red[tid] = v0 + v1;
    __syncthreads();
    for (int off = 128; off > 0; off >>= 1) {
        if (tid < off) red[tid] += red[tid + off];
        __syncthreads();
    }
    float mean = red[0] / 512.f;
    __syncthreads();
    float d0 = v0 - mean, d1 = v1 - mean;
    red[tid] = d0 * d0 + d1 * d1;
    __syncthreads();
    for (int off = 128; off > 0; off >>= 1) {
        if (tid < off) red[tid] += red[tid + off];
        __syncthreads();
    }
    float var = red[0] / 512.f;
    float rs = 1.0f / sqrtf(var + 1e-5f);
    float y0 = d0 * rs * g[tid] + bvec[tid];
    float y1 = d1 * rs * g[tid + 256] + bvec[tid + 256];
    out[(size_t)row * D_ + tid] = y0;
    out[(size_t)row * D_ + tid + 256] = y1;
    if (BFC) {
        bfout[(size_t)row * D_ + tid] = __float2bfloat16(y0);
        bfout[(size_t)row * D_ + tid + 256] = __float2bfloat16(y1);
    }
}

// ---------------------------------------------------------------------------
extern "C" void kernel_launch(void* const* d_in, const int* in_sizes, int n_in,
                              void* d_out, int out_size, void* d_ws, size_t ws_size,
                              hipStream_t stream)
{
    (void)in_sizes; (void)n_in; (void)out_size; (void)ws_size;
    const float* dec   = (const float*)d_in[0];
    const float* enc   = (const float*)d_in[1];
    const float* sa_Wq = (const float*)d_in[2];
    const float* sa_Wk = (const float*)d_in[3];
    const float* sa_Wv = (const float*)d_in[4];
    const float* sa_Wo = (const float*)d_in[5];
    const float* sa_g  = (const float*)d_in[6];
    const float* sa_b  = (const float*)d_in[7];
    const float* sa_rot= (const float*)d_in[8];
    const float* ca_Wq = (const float*)d_in[9];
    const float* ca_Wk = (const float*)d_in[10];
    const float* ca_Wv = (const float*)d_in[11];
    const float* ca_Wo = (const float*)d_in[12];
    const float* ca_g  = (const float*)d_in[13];
    const float* ca_b  = (const float*)d_in[14];
    const float* ca_rot= (const float*)d_in[15];
    const float* ff_W1 = (const float*)d_in[16];
    const float* ff_b1 = (const float*)d_in[17];
    const float* ff_W2 = (const float*)d_in[18];
    const float* ff_b2 = (const float*)d_in[19];
    const float* ff_g  = (const float*)d_in[20];
    const float* ff_b  = (const float*)d_in[21];

    char* ws = (char*)d_ws;
    const size_t MB = 1ull << 20;
    // SA phase (f32)
    float* qb     = (float*)(ws + 0);        // 32MB
    float* kb     = (float*)(ws + 32*MB);    // 32MB
    float* vb     = (float*)(ws + 64*MB);    // 32MB
    float* ob     = (float*)(ws + 96*MB);    // 32MB
    float* act0   = (float*)(ws + 128*MB);   // 32MB (live thru ca_Wo residual)
    bf16*  act0bf = (bf16*)(ws + 160*MB);    // 16MB
    // CA hash projections (overlay dead qb/kb region, consumed before cq/ck)
    float* rq     = (float*)(ws + 0);        // 16.8MB
    float* rk     = (float*)(ws + 17*MB);    // 16.8MB
    // CA phase overlays
    bf16*  cq     = (bf16*)(ws + 0);         // 16MB
    bf16*  ck     = (bf16*)(ws + 16*MB);     // 16MB
    bf16*  cv     = (bf16*)(ws + 32*MB);     // 16MB
    bf16*  caOut  = (bf16*)(ws + 48*MB);     // 16MB
    bf16*  encbf  = (bf16*)(ws + 64*MB);     // 16MB
    bf16*  act1bf = (bf16*)(ws + 80*MB);     // 16MB
    float* act1   = (float*)(ws + 96*MB);    // 32MB
    // FF overlays (cq..caOut dead)
    bf16*  hid    = (bf16*)(ws + 0);         // 64MB
    float* ffout  = (float*)(ws + 128*MB);   // 32MB (act0 dead)
    // weights / hash
    bf16*  caWqt  = (bf16*)(ws + 176*MB);
    bf16*  caWkt  = (bf16*)(ws + 176*MB + 512*1024);
    bf16*  caWvt  = (bf16*)(ws + 177*MB);
    bf16*  caWot  = (bf16*)(ws + 177*MB + 512*1024);
    bf16*  ffW1t  = (bf16*)(ws + 178*MB);    // 2MB
    bf16*  ffW2t  = (bf16*)(ws + 180*MB);    // 2MB
    float* wrotq  = (float*)(ws + 182*MB);
    float* wrotk  = (float*)(ws + 182*MB + 512*1024);
    int*   bqb    = (int*)(ws + 183*MB);
    int*   bkb    = (int*)(ws + 183*MB + 512*1024);
    int*   pqb    = (int*)(ws + 184*MB);
    int*   pkb    = (int*)(ws + 184*MB + 512*1024);   // ends at 185MB

    dim3 blk(256);
    const int g512  = (M_ / 128) * (512 / 128);    // 512 blocks
    const int g256  = (M_ / 128) * (256 / 128);    // 256 blocks (proj)
    const int g2048 = (M_ / 128) * (2048 / 128);   // 2048 blocks

    // ---- converters (independent) ----
    wrot_k<<<512, blk, 0, stream>>>(ca_Wq, ca_rot, wrotq);
    wrot_k<<<512, blk, 0, stream>>>(ca_Wk, ca_rot, wrotk);
    convw_k<<<1024, blk, 0, stream>>>(ca_Wq, caWqt, 512, 512);
    convw_k<<<1024, blk, 0, stream>>>(ca_Wk, caWkt, 512, 512);
    convw_k<<<1024, blk, 0, stream>>>(ca_Wv, caWvt, 512, 512);
    convw_k<<<1024, blk, 0, stream>>>(ca_Wo, caWot, 512, 512);
    convw_k<<<4096, blk, 0, stream>>>(ff_W1, ffW1t, 2048, 512);
    convw_k<<<4096, blk, 0, stream>>>(ff_W2, ffW2t, 512, 2048);

    // ---------------- self-attention (f32-class, feeds ca-hash) ----------
    gemm_k<1,0><<<g512, blk, 0, stream>>>(dec, sa_Wq, nullptr, qb, 512, 512);
    gemm_k<1,0><<<g512, blk, 0, stream>>>(dec, sa_Wk, nullptr, kb, 512, 512);
    gemm_k<1,0><<<g512, blk, 0, stream>>>(dec, sa_Wv, nullptr, vb, 512, 512);
    hash_k<<<BH_ * 16, blk, 0, stream>>>(qb, sa_rot, bqb);
    hash_k<<<BH_ * 16, blk, 0, stream>>>(kb, sa_rot, bkb);
    sort_k<<<BH_, blk, 0, stream>>>(bqb, pqb);
    sort_k<<<BH_, blk, 0, stream>>>(bkb, pkb);
    attn_k<float,float><<<BH_ * NC_, blk, 0, stream>>>(qb, kb, vb, bqb, bkb, pqb, pkb, ob);
    gemm_k<0,1><<<g512, blk, 0, stream>>>(ob, sa_Wo, dec, act0, 512, 512);
    ln_k<true><<<M_, blk, 0, stream>>>(act0, sa_g, sa_b, act0, act0bf);

    // ---------------- cross-attention ----------------
    gemm_k<0,0><<<g256, blk, 0, stream>>>(act0, wrotq, nullptr, rq, 256, 512);
    gemm_k<0,0><<<g256, blk, 0, stream>>>(enc,  wrotk, nullptr, rk, 256, 512);
    amax_k<<<M_ * 8 / 256, blk, 0, stream>>>(rq, bqb);
    amax_k<<<M_ * 8 / 256, blk, 0, stream>>>(rk, bkb);
    sort_k<<<BH_, blk, 0, stream>>>(bqb, pqb);
    sort_k<<<BH_, blk, 0, stream>>>(bkb, pkb);
    cast_k<<<M_ * 512 / 1024, blk, 0, stream>>>(enc, encbf);
    mgemm_k<2,0,false,false><<<g512, blk, 0, stream>>>((const short*)act0bf, (const short*)caWqt, nullptr, nullptr, cq, 512, 512);
    mgemm_k<2,0,false,false><<<g512, blk, 0, stream>>>((const short*)encbf, (const short*)caWkt, nullptr, nullptr, ck, 512, 512);
    mgemm_k<2,0,false,false><<<g512, blk, 0, stream>>>((const short*)encbf, (const short*)caWvt, nullptr, nullptr, cv, 512, 512);
    attn_k<bf16,bf16><<<BH_ * NC_, blk, 0, stream>>>(cq, ck, cv, bqb, bkb, pqb, pkb, caOut);
    mgemm_k<0,1,false,false><<<g512, blk, 0, stream>>>((const short*)caOut, (const short*)caWot, nullptr, act0, act1, 512, 512);
    ln_k<true><<<M_, blk, 0, stream>>>(act1, ca_g, ca_b, act1, act1bf);

    // ---------------- feed-forward ----------------
    mgemm_k<1,0,true,true><<<g2048, blk, 0, stream>>>((const short*)act1bf, (const short*)ffW1t, ff_b1, nullptr, hid, 2048, 512);
    mgemm_k<0,1,true,false><<<g512, blk, 0, stream>>>((const short*)hid, (const short*)ffW2t, ff_b2, act1, ffout, 512, 2048);
    ln_k<false><<<M_, blk, 0, stream>>>(ffout, ff_g, ff_b, (float*)d_out, nullptr);
}

// Round 8
// 1159.444 us; speedup vs baseline: 3.8492x; 1.0703x over previous
//
#include <hip/hip_runtime.h>
#include <hip/hip_bf16.h>
#include <math.h>

typedef __hip_bfloat16 bf16;

#define B_ 4
#define S_ 4096
#define D_ 512
#define H_ 8
#define NC_ 64
#define M_ (B_*S_)     // 16384
#define BH_ (B_*H_)    // 32

typedef __attribute__((ext_vector_type(8))) short bfrag;   // 8 bf16 (4 VGPRs)
typedef __attribute__((ext_vector_type(4))) float facc;    // 4 f32 acc

static __device__ __forceinline__ float tof(float x){ return x; }
static __device__ __forceinline__ float tof(bf16 x){ return __bfloat162float(x); }

static __device__ __forceinline__ float4 ld4g(const float* p) {
    return *reinterpret_cast<const float4*>(p);
}
static __device__ __forceinline__ float4 ld4g(const bf16* p) {
    short4 s = *reinterpret_cast<const short4*>(p);
    float4 r;
    r.x = __bfloat162float(*reinterpret_cast<const bf16*>(&s.x));
    r.y = __bfloat162float(*reinterpret_cast<const bf16*>(&s.y));
    r.z = __bfloat162float(*reinterpret_cast<const bf16*>(&s.z));
    r.w = __bfloat162float(*reinterpret_cast<const bf16*>(&s.w));
    return r;
}
static __device__ __forceinline__ void st4(float* p, float4 v) {
    *reinterpret_cast<float4*>(p) = v;
}
static __device__ __forceinline__ void st4(bf16* p, float4 v) {
    bf16 b0 = __float2bfloat16(v.x), b1 = __float2bfloat16(v.y);
    bf16 b2 = __float2bfloat16(v.z), b3 = __float2bfloat16(v.w);
    short4 s;
    s.x = *reinterpret_cast<short*>(&b0);
    s.y = *reinterpret_cast<short*>(&b1);
    s.z = *reinterpret_cast<short*>(&b2);
    s.w = *reinterpret_cast<short*>(&b3);
    *reinterpret_cast<short4*>(p) = s;
}

#define GLL(gp, lp) __builtin_amdgcn_global_load_lds( \
    (const __attribute__((address_space(1))) void*)(gp), \
    (__attribute__((address_space(3))) void*)(lp), 16, 0, 0)

// ---------------------------------------------------------------------------
// f32 VALU GEMM (hash-feeding paths; f32-class accuracy required).
// Round-8 geometry: A staged TRANSPOSED via regs into At[32][132] (pad ->
// b128 reads conflict-free); B staged linear [kk][128] via global_load_lds.
// MAC loop: 4 x b128 LDS reads + 64 FMA per kk. Numerically bit-identical
// to previous rounds (same per-element accumulation order).
// OUTMODE: 0 = f32 RM, 1 = qkv-scatter. RES: 0 none, 1 f32 residual.
// ---------------------------------------------------------------------------
template<int OUTMODE, int RES>
__global__ __launch_bounds__(256) void gemm_k(
    const float* __restrict__ A, const float* __restrict__ Bw,
    const float* __restrict__ res, float* __restrict__ out, int N, int K)
{
    const int BK = 32;
    __shared__ float At[32][132];    // [kk][row] transposed, padded (16.5KB)
    __shared__ float Bs[32 * 128];   // [kk][col] linear (16KB)

    int tid = threadIdx.x;
    int wave = tid >> 6;
    int nbx = N >> 7;
    int bx = blockIdx.x % nbx;
    int by = blockIdx.x / nbx;
    int row0 = by << 7;
    int col0 = bx << 7;
    int ty = tid >> 4;   // 0..15 -> rows ty*8..+7
    int tx = tid & 15;   // 0..15 -> cols tx*4+{0..3} and +64

    float acc[8][8];     // [i=row][j]: col = (j>=4)*64 + tx*4 + (j&3)
    #pragma unroll
    for (int i = 0; i < 8; i++)
        #pragma unroll
        for (int j = 0; j < 8; j++) acc[i][j] = 0.f;

    for (int k0 = 0; k0 < K; k0 += BK) {
        // B tile 32x128 (GLL linear): e = c*256+tid, kk=e>>5, col4=(e&31)*4
        #pragma unroll
        for (int c = 0; c < 4; c++) {
            int e = c * 256 + tid;
            GLL(Bw + (size_t)(k0 + (e >> 5)) * N + col0 + ((e & 31) << 2),
                &Bs[c * 1024 + (wave << 8)]);
        }
        // A tile 128x32, reg-staged transposed: r=e>>3, k4=(e&7)*4
        #pragma unroll
        for (int c = 0; c < 4; c++) {
            int e = c * 256 + tid;
            int r = e >> 3, k4 = (e & 7) << 2;
            float4 t4 = ld4g(A + (size_t)(row0 + r) * K + k0 + k4);
            At[k4 + 0][r] = t4.x;
            At[k4 + 1][r] = t4.y;
            At[k4 + 2][r] = t4.z;
            At[k4 + 3][r] = t4.w;
        }
        __syncthreads();
        #pragma unroll
        for (int kk = 0; kk < BK; kk++) {
            float4 a0 = *reinterpret_cast<const float4*>(&At[kk][ty * 8]);
            float4 a1 = *reinterpret_cast<const float4*>(&At[kk][ty * 8 + 4]);
            float4 b0 = *reinterpret_cast<const float4*>(&Bs[kk * 128 + tx * 4]);
            float4 b1 = *reinterpret_cast<const float4*>(&Bs[kk * 128 + 64 + tx * 4]);
            float a[8] = {a0.x, a0.y, a0.z, a0.w, a1.x, a1.y, a1.z, a1.w};
            float bb[8] = {b0.x, b0.y, b0.z, b0.w, b1.x, b1.y, b1.z, b1.w};
            #pragma unroll
            for (int i = 0; i < 8; i++)
                #pragma unroll
                for (int j = 0; j < 8; j++) acc[i][j] += a[i] * bb[j];
        }
        __syncthreads();
    }

    #pragma unroll
    for (int i = 0; i < 8; i++) {
        int r = row0 + ty * 8 + i;
        #pragma unroll
        for (int j = 0; j < 8; j++) {
            int c = col0 + ((j >> 2) << 6) + tx * 4 + (j & 3);
            float v = acc[i][j];
            if (RES == 1) v += res[(size_t)r * N + c];
            if (OUTMODE == 0) {
                out[(size_t)r * N + c] = v;
            } else {
                int b = r >> 12, s = r & (S_ - 1);
                int h = c >> 6, kk2 = c & 63;
                out[((size_t)(b * H_ + h) * S_ + s) * 64 + kk2] = v;
            }
        }
    }
}

// ---------------------------------------------------------------------------
// bf16 MFMA GEMM (post-hash smooth path). A: [M,K] bf16 RM. Bt: [N,K] bf16.
// ---------------------------------------------------------------------------
template<int OUTMODE, int RES, bool BIAS, bool RELU>
__global__ __launch_bounds__(256) void mgemm_k(
    const short* __restrict__ A, const short* __restrict__ Bt,
    const float* __restrict__ bias, const float* __restrict__ res,
    void* __restrict__ out, int N, int K)
{
    __shared__ short As[128 * 32];
    __shared__ short Bs[128 * 32];

    int tid = threadIdx.x;
    int wave = tid >> 6, lane = tid & 63;
    int nbx = N >> 7;
    int bx = blockIdx.x % nbx, by = blockIdx.x / nbx;
    int row0 = by << 7, col0 = bx << 7;
    int wr = wave >> 1, wc = wave & 1;   // 64x64 wave tile
    int fr = lane & 15, fq = lane >> 4;

    facc acc[4][4];
    facc zero = {0.f, 0.f, 0.f, 0.f};
    #pragma unroll
    for (int m = 0; m < 4; m++)
        #pragma unroll
        for (int n = 0; n < 4; n++) acc[m][n] = zero;

    const short* gA = A + (size_t)(row0 + (wave << 5) + (lane >> 2)) * K + ((lane & 3) << 3);
    const short* gB = Bt + (size_t)(col0 + (wave << 5) + (lane >> 2)) * K + ((lane & 3) << 3);

    for (int k0 = 0; k0 < K; k0 += 32) {
        GLL(gA + k0,                 &As[wave << 10]);
        GLL(gA + k0 + (size_t)16 * K, &As[(wave << 10) + 512]);
        GLL(gB + k0,                 &Bs[wave << 10]);
        GLL(gB + k0 + (size_t)16 * K, &Bs[(wave << 10) + 512]);
        __syncthreads();

        bfrag av[4], bv[4];
        #pragma unroll
        for (int m = 0; m < 4; m++)
            av[m] = *reinterpret_cast<const bfrag*>(&As[(((wr << 6) + (m << 4) + fr) << 5) + (fq << 3)]);
        #pragma unroll
        for (int n = 0; n < 4; n++)
            bv[n] = *reinterpret_cast<const bfrag*>(&Bs[(((wc << 6) + (n << 4) + fr) << 5) + (fq << 3)]);
        #pragma unroll
        for (int m = 0; m < 4; m++)
            #pragma unroll
            for (int n = 0; n < 4; n++)
                acc[m][n] = __builtin_amdgcn_mfma_f32_16x16x32_bf16(av[m], bv[n], acc[m][n], 0, 0, 0);
        __syncthreads();
    }

    #pragma unroll
    for (int m = 0; m < 4; m++) {
        #pragma unroll
        for (int n = 0; n < 4; n++) {
            #pragma unroll
            for (int r = 0; r < 4; r++) {
                int row = row0 + (wr << 6) + (m << 4) + (fq << 2) + r;
                int col = col0 + (wc << 6) + (n << 4) + fr;
                float v = acc[m][n][r];
                if (BIAS) v += bias[col];
                if (RELU) v = fmaxf(v, 0.f);
                if (RES == 1) v += res[(size_t)row * N + col];
                if (OUTMODE == 0) {
                    ((float*)out)[(size_t)row * N + col] = v;
                } else if (OUTMODE == 1) {
                    ((bf16*)out)[(size_t)row * N + col] = __float2bfloat16(v);
                } else {
                    int b = row >> 12, s = row & (S_ - 1);
                    int h = col >> 6, kk2 = col & 63;
                    ((bf16*)out)[(((size_t)(b * H_ + h) * S_ + s) << 6) + kk2] = __float2bfloat16(v);
                }
            }
        }
    }
}

// ---------------------------------------------------------------------------
// Weight converters
// ---------------------------------------------------------------------------
__global__ __launch_bounds__(256) void convw_k(
    const float* __restrict__ W, bf16* __restrict__ Wt, int N, int K)
{
    int i = blockIdx.x * 256 + threadIdx.x;
    int n = i / K, k = i % K;
    Wt[i] = __float2bfloat16(W[(size_t)k * N + n]);
}

__global__ __launch_bounds__(256) void wrot_k(
    const float* __restrict__ W, const float* __restrict__ rot,
    float* __restrict__ wrot)
{
    int d = blockIdx.x, t = threadIdx.x;
    int h = t >> 5, j = t & 31;
    float a = 0.f;
    #pragma unroll
    for (int k = 0; k < 64; k++)
        a += W[(size_t)(d * H_ + h) * 64 + k] * rot[(size_t)(h * 64 + k) * 32 + j];
    wrot[(size_t)d * 256 + t] = a;
}

__global__ __launch_bounds__(256) void cast_k(
    const float* __restrict__ x, bf16* __restrict__ y)
{
    size_t i = ((size_t)blockIdx.x * 256 + threadIdx.x) * 4;
    float4 v = *reinterpret_cast<const float4*>(x + i);
    y[i]     = __float2bfloat16(v.x);
    y[i + 1] = __float2bfloat16(v.y);
    y[i + 2] = __float2bfloat16(v.z);
    y[i + 3] = __float2bfloat16(v.w);
}

// ---------------------------------------------------------------------------
// SA hash (from f32 q/k scatter layout)
// ---------------------------------------------------------------------------
__global__ __launch_bounds__(256) void hash_k(
    const float* __restrict__ t, const float* __restrict__ rot,
    int* __restrict__ bucket)
{
    int bh = blockIdx.x >> 4;
    int st = blockIdx.x & 15;
    int h = bh % H_;
    __shared__ float rs[64][32];
    int tid = threadIdx.x;
    for (int e = tid; e < 2048; e += 256)
        rs[e >> 5][e & 31] = rot[h * 2048 + e];
    __syncthreads();

    int s = st * 256 + tid;
    const float* qr = t + ((size_t)bh * S_ + s) * 64;
    float qv[64];
    #pragma unroll
    for (int i = 0; i < 64; i++) qv[i] = qr[i];
    float r[32];
    #pragma unroll
    for (int j = 0; j < 32; j++) {
        float a = 0.f;
        #pragma unroll
        for (int kk = 0; kk < 64; kk++) a += qv[kk] * rs[kk][j];
        r[j] = a;
    }
    float best = -INFINITY; int bi = 0;
    #pragma unroll
    for (int j = 0; j < 32; j++) { if (r[j] > best) { best = r[j]; bi = j; } }
    #pragma unroll
    for (int j = 0; j < 32; j++) { float v = -r[j]; if (v > best) { best = v; bi = 32 + j; } }
    bucket[(size_t)bh * S_ + s] = bi;
}

// ---------------------------------------------------------------------------
// CA hash argmax from projection r [M,256] (col = h*32+j).
// ---------------------------------------------------------------------------
__global__ __launch_bounds__(256) void amax_k(
    const float* __restrict__ r, int* __restrict__ bucket)
{
    int idx = blockIdx.x * 256 + threadIdx.x;
    int row = idx >> 3, h = idx & 7;
    const float* rr = r + (size_t)row * 256 + h * 32;
    float best = -INFINITY; int bi = 0;
    #pragma unroll
    for (int j = 0; j < 32; j++) { float v = rr[j]; if (v > best) { best = v; bi = j; } }
    #pragma unroll
    for (int j = 0; j < 32; j++) { float v = -rr[j]; if (v > best) { best = v; bi = 32 + j; } }
    int b = row >> 12, s = row & (S_ - 1);
    bucket[((size_t)(b * H_ + h)) * S_ + s] = bi;
}

// ---------------------------------------------------------------------------
// Parallel stable counting sort per (b,h) — exact argsort(bucket*S + pos).
// ---------------------------------------------------------------------------
__global__ __launch_bounds__(256) void sort_k(
    const int* __restrict__ bucket, int* __restrict__ perm)
{
    int bh = blockIdx.x;
    __shared__ int lb[S_];          // 16 KB
    __shared__ int cnt[64 * 128];   // 32 KB  cnt[b*128 + s]
    __shared__ int wtot[4];
    int tid = threadIdx.x;

    for (int i = tid; i < S_; i += 256) lb[i] = bucket[(size_t)bh * S_ + i];
    for (int i = tid; i < 8192; i += 256) cnt[i] = 0;
    __syncthreads();

    if (tid < 128) {
        int s0 = tid << 5;
        #pragma unroll
        for (int i = 0; i < 32; i++)
            cnt[(lb[s0 + i] << 7) + tid]++;
    }
    __syncthreads();

    int base = tid << 5;
    int tsum = 0;
    #pragma unroll
    for (int i = 0; i < 32; i++) tsum += cnt[base + i];
    int incl = tsum;
    #pragma unroll
    for (int off = 1; off < 64; off <<= 1) {
        int n = __shfl_up(incl, off, 64);
        if ((tid & 63) >= off) incl += n;
    }
    if ((tid & 63) == 63) wtot[tid >> 6] = incl;
    __syncthreads();
    int wbase = 0;
    for (int w = 0; w < (tid >> 6); w++) wbase += wtot[w];
    int run = wbase + incl - tsum;
    #pragma unroll
    for (int i = 0; i < 32; i++) {
        int c = cnt[base + i];
        cnt[base + i] = run;
        run += c;
    }
    __syncthreads();

    if (tid < 128) {
        int s0 = tid << 5;
        int* pr = perm + (size_t)bh * S_;
        #pragma unroll
        for (int i = 0; i < 32; i++) {
            int b = lb[s0 + i];
            int pos = cnt[(b << 7) + tid]++;
            pr[pos] = s0 + i;
        }
    }
}

// ---------------------------------------------------------------------------
// Chunked LSH attention: 4 waves/block, quad-per-query (round-5 structure).
// ---------------------------------------------------------------------------
template<typename T, typename OT>
__global__ __launch_bounds__(256, 4) void attn_k(
    const T* __restrict__ q, const T* __restrict__ k,
    const T* __restrict__ v, const int* __restrict__ bq,
    const int* __restrict__ bk, const int* __restrict__ permq,
    const int* __restrict__ permk, OT* __restrict__ o)
{
    int c = blockIdx.x % NC_;
    int bh = blockIdx.x / NC_;
    int b = bh / H_, h = bh % H_;
    __shared__ float kv[128][64];
    __shared__ int skx[128];
    __shared__ int bkx[128];
    int tid = threadIdx.x;
    const int qq = tid >> 2, u = tid & 3;
    const size_t bhS = (size_t)bh * S_;

    if (tid < 128) {
        int sidx = (tid < 64) ? (((c + NC_ - 1) & (NC_ - 1)) * 64 + tid)
                              : (c * 64 + (tid - 64));
        int sk = permk[bhS + sidx];
        skx[tid] = sk;
        bkx[tid] = bk[bhS + sk];
    }
    __syncthreads();

    {
        int rr = tid >> 4, c4 = (tid & 15) << 2;
        #pragma unroll
        for (int pass = 0; pass < 8; pass++) {
            int row = pass * 16 + rr;
            *reinterpret_cast<float4*>(&kv[row][c4]) =
                ld4g(k + (bhS + skx[row]) * 64 + c4);
        }
    }

    int sq = permq[bhS + c * 64 + qq];
    float4 qv[4];
    {
        const T* qr = q + (bhS + sq) * 64 + u * 16;
        #pragma unroll
        for (int i = 0; i < 4; i++) qv[i] = ld4g(qr + i * 4);
    }
    int bqi = bq[bhS + sq];
    __syncthreads();

    float p[32];
    #pragma unroll
    for (int g = 0; g < 4; g++) {
        float part[32];
        #pragma unroll
        for (int t = 0; t < 32; t++) {
            const float4* kr = reinterpret_cast<const float4*>(&kv[g * 32 + t][u << 4]);
            float4 k0 = kr[0], k1 = kr[1], k2 = kr[2], k3 = kr[3];
            float s0 = qv[0].x * k0.x + qv[0].y * k0.y + qv[0].z * k0.z + qv[0].w * k0.w;
            float s1 = qv[1].x * k1.x + qv[1].y * k1.y + qv[1].z * k1.z + qv[1].w * k1.w;
            float s2 = qv[2].x * k2.x + qv[2].y * k2.y + qv[2].z * k2.z + qv[2].w * k2.w;
            float s3 = qv[3].x * k3.x + qv[3].y * k3.y + qv[3].z * k3.z + qv[3].w * k3.w;
            part[t] = (s0 + s1) + (s2 + s3);
        }
        float keep[16];
        #pragma unroll
        for (int t = 0; t < 16; t++) {
            float lo = __shfl_xor(part[t], 2, 64);
            float hi = __shfl_xor(part[16 + t], 2, 64);
            keep[t] = (u < 2) ? part[t] + lo : part[16 + t] + hi;
        }
        #pragma unroll
        for (int t = 0; t < 8; t++) {
            float lo = __shfl_xor(keep[t], 1, 64);
            float hi = __shfl_xor(keep[8 + t], 1, 64);
            float s = ((u & 1) == 0) ? keep[t] + lo : keep[8 + t] + hi;
            int j = g * 32 + (u >> 1) * 16 + (u & 1) * 8 + t;
            p[g * 8 + t] = (bqi == bkx[j]) ? s * 0.125f : -1e9f;
        }
    }

    float m = -INFINITY;
    #pragma unroll
    for (int i = 0; i < 32; i++) m = fmaxf(m, p[i]);
    m = fmaxf(m, __shfl_xor(m, 1, 64));
    m = fmaxf(m, __shfl_xor(m, 2, 64));
    float l = 0.f;
    #pragma unroll
    for (int i = 0; i < 32; i++) { p[i] = __expf(p[i] - m); l += p[i]; }
    l += __shfl_xor(l, 1, 64);
    l += __shfl_xor(l, 2, 64);

    __syncthreads();
    {
        int rr = tid >> 4, c4 = (tid & 15) << 2;
        #pragma unroll
        for (int pass = 0; pass < 8; pass++) {
            int row = pass * 16 + rr;
            *reinterpret_cast<float4*>(&kv[row][c4]) =
                ld4g(v + (bhS + skx[row]) * 64 + c4);
        }
    }
    __syncthreads();

    float4 acc0 = make_float4(0.f, 0.f, 0.f, 0.f);
    float4 acc1 = make_float4(0.f, 0.f, 0.f, 0.f);
    float4 acc2 = make_float4(0.f, 0.f, 0.f, 0.f);
    float4 acc3 = make_float4(0.f, 0.f, 0.f, 0.f);
    int base = tid & ~3;
    #pragma unroll
    for (int j = 0; j < 128; j++) {
        const int uo = ((j >> 3) & 1) | (((j >> 4) & 1) << 1);
        const int slot = ((j >> 5) << 3) | (j & 7);
        float pj = __shfl(p[slot], base + uo, 64);
        const float4* vr = reinterpret_cast<const float4*>(&kv[j][u << 4]);
        float4 v0 = vr[0], v1 = vr[1], v2 = vr[2], v3 = vr[3];
        acc0.x += pj * v0.x; acc0.y += pj * v0.y; acc0.z += pj * v0.z; acc0.w += pj * v0.w;
        acc1.x += pj * v1.x; acc1.y += pj * v1.y; acc1.z += pj * v1.z; acc1.w += pj * v1.w;
        acc2.x += pj * v2.x; acc2.y += pj * v2.y; acc2.z += pj * v2.z; acc2.w += pj * v2.w;
        acc3.x += pj * v3.x; acc3.y += pj * v3.y; acc3.z += pj * v3.z; acc3.w += pj * v3.w;
    }
    float inv = 1.0f / l;
    OT* orow = o + ((size_t)b * S_ + sq) * 512 + h * 64 + (u << 4);
    st4(orow + 0,  make_float4(acc0.x * inv, acc0.y * inv, acc0.z * inv, acc0.w * inv));
    st4(orow + 4,  make_float4(acc1.x * inv, acc1.y * inv, acc1.z * inv, acc1.w * inv));
    st4(orow + 8,  make_float4(acc2.x * inv, acc2.y * inv, acc2.z * inv, acc2.w * inv));
    st4(orow + 12, make_float4(acc3.x * inv, acc3.y * inv, acc3.z * inv, acc3.w * inv));
}

// ---------------------------------------------------------------------------
// LayerNorm per row of [M,512], f32 out (+ optional bf16 copy).
// ---------------------------------------------------------------------------
template<bool BFC>
__global__ __launch_bounds__(256) void ln_k(
    const float* __restrict__ x, const float* __restrict__ g,
    const float* __restrict__ bvec, float* __restrict__ out,
    bf16* __restrict__ bfout)
{
    int row = blockIdx.x;
    int tid = threadIdx.x;
    __shared__ float red[256];
    const float* xr = x + (size_t)row * D_;
    float v0 = xr[tid], v1 = xr[tid + 256];
    red[tid] = v0 + v1;
    __syncthreads();
    for (int off = 128; off > 0; off >>= 1) {
        if (tid < off) red[tid] += red[tid + off];
        __syncthreads();
    }
    float mean = red[0] / 512.f;
    __syncthreads();
    float d0 = v0 - mean, d1 = v1 - mean;
    red[tid] = d0 * d0 + d1 * d1;
    __syncthreads();
    for (int off = 128; off > 0; off >>= 1) {
        if (tid < off) red[tid] += red[tid + off];
        __syncthreads();
    }
    float var = red[0] / 512.f;
    float rs = 1.0f / sqrtf(var + 1e-5f);
    float y0 = d0 * rs * g[tid] + bvec[tid];
    float y1 = d1 * rs * g[tid + 256] + bvec[tid + 256];
    out[(size_t)row * D_ + tid] = y0;
    out[(size_t)row * D_ + tid + 256] = y1;
    if (BFC) {
        bfout[(size_t)row * D_ + tid] = __float2bfloat16(y0);
        bfout[(size_t)row * D_ + tid + 256] = __float2bfloat16(y1);
    }
}

// ---------------------------------------------------------------------------
extern "C" void kernel_launch(void* const* d_in, const int* in_sizes, int n_in,
                              void* d_out, int out_size, void* d_ws, size_t ws_size,
                              hipStream_t stream)
{
    (void)in_sizes; (void)n_in; (void)out_size; (void)ws_size;
    const float* dec   = (const float*)d_in[0];
    const float* enc   = (const float*)d_in[1];
    const float* sa_Wq = (const float*)d_in[2];
    const float* sa_Wk = (const float*)d_in[3];
    const float* sa_Wv = (const float*)d_in[4];
    const float* sa_Wo = (const float*)d_in[5];
    const float* sa_g  = (const float*)d_in[6];
    const float* sa_b  = (const float*)d_in[7];
    const float* sa_rot= (const float*)d_in[8];
    const float* ca_Wq = (const float*)d_in[9];
    const float* ca_Wk = (const float*)d_in[10];
    const float* ca_Wv = (const float*)d_in[11];
    const float* ca_Wo = (const float*)d_in[12];
    const float* ca_g  = (const float*)d_in[13];
    const float* ca_b  = (const float*)d_in[14];
    const float* ca_rot= (const float*)d_in[15];
    const float* ff_W1 = (const float*)d_in[16];
    const float* ff_b1 = (const float*)d_in[17];
    const float* ff_W2 = (const float*)d_in[18];
    const float* ff_b2 = (const float*)d_in[19];
    const float* ff_g  = (const float*)d_in[20];
    const float* ff_b  = (const float*)d_in[21];

    char* ws = (char*)d_ws;
    const size_t MB = 1ull << 20;
    // SA phase (f32)
    float* qb     = (float*)(ws + 0);        // 32MB
    float* kb     = (float*)(ws + 32*MB);    // 32MB
    float* vb     = (float*)(ws + 64*MB);    // 32MB
    float* ob     = (float*)(ws + 96*MB);    // 32MB
    float* act0   = (float*)(ws + 128*MB);   // 32MB (live thru ca_Wo residual)
    bf16*  act0bf = (bf16*)(ws + 160*MB);    // 16MB
    // CA hash projections (overlay dead qb/kb region, consumed before cq/ck)
    float* rq     = (float*)(ws + 0);        // 16.8MB
    float* rk     = (float*)(ws + 17*MB);    // 16.8MB
    // CA phase overlays
    bf16*  cq     = (bf16*)(ws + 0);         // 16MB
    bf16*  ck     = (bf16*)(ws + 16*MB);     // 16MB
    bf16*  cv     = (bf16*)(ws + 32*MB);     // 16MB
    bf16*  caOut  = (bf16*)(ws + 48*MB);     // 16MB
    bf16*  encbf  = (bf16*)(ws + 64*MB);     // 16MB
    bf16*  act1bf = (bf16*)(ws + 80*MB);     // 16MB
    float* act1   = (float*)(ws + 96*MB);    // 32MB
    // FF overlays (cq..caOut dead)
    bf16*  hid    = (bf16*)(ws + 0);         // 64MB
    float* ffout  = (float*)(ws + 128*MB);   // 32MB (act0 dead)
    // weights / hash
    bf16*  caWqt  = (bf16*)(ws + 176*MB);
    bf16*  caWkt  = (bf16*)(ws + 176*MB + 512*1024);
    bf16*  caWvt  = (bf16*)(ws + 177*MB);
    bf16*  caWot  = (bf16*)(ws + 177*MB + 512*1024);
    bf16*  ffW1t  = (bf16*)(ws + 178*MB);    // 2MB
    bf16*  ffW2t  = (bf16*)(ws + 180*MB);    // 2MB
    float* wrotq  = (float*)(ws + 182*MB);
    float* wrotk  = (float*)(ws + 182*MB + 512*1024);
    int*   bqb    = (int*)(ws + 183*MB);
    int*   bkb    = (int*)(ws + 183*MB + 512*1024);
    int*   pqb    = (int*)(ws + 184*MB);
    int*   pkb    = (int*)(ws + 184*MB + 512*1024);   // ends at 185MB

    dim3 blk(256);
    const int g512  = (M_ / 128) * (512 / 128);    // 512 blocks
    const int g256  = (M_ / 128) * (256 / 128);    // 256 blocks (proj)
    const int g2048 = (M_ / 128) * (2048 / 128);   // 2048 blocks

    // ---- converters (independent) ----
    wrot_k<<<512, blk, 0, stream>>>(ca_Wq, ca_rot, wrotq);
    wrot_k<<<512, blk, 0, stream>>>(ca_Wk, ca_rot, wrotk);
    convw_k<<<1024, blk, 0, stream>>>(ca_Wq, caWqt, 512, 512);
    convw_k<<<1024, blk, 0, stream>>>(ca_Wk, caWkt, 512, 512);
    convw_k<<<1024, blk, 0, stream>>>(ca_Wv, caWvt, 512, 512);
    convw_k<<<1024, blk, 0, stream>>>(ca_Wo, caWot, 512, 512);
    convw_k<<<4096, blk, 0, stream>>>(ff_W1, ffW1t, 2048, 512);
    convw_k<<<4096, blk, 0, stream>>>(ff_W2, ffW2t, 512, 2048);

    // ---------------- self-attention (f32-class, feeds ca-hash) ----------
    gemm_k<1,0><<<g512, blk, 0, stream>>>(dec, sa_Wq, nullptr, qb, 512, 512);
    gemm_k<1,0><<<g512, blk, 0, stream>>>(dec, sa_Wk, nullptr, kb, 512, 512);
    gemm_k<1,0><<<g512, blk, 0, stream>>>(dec, sa_Wv, nullptr, vb, 512, 512);
    hash_k<<<BH_ * 16, blk, 0, stream>>>(qb, sa_rot, bqb);
    hash_k<<<BH_ * 16, blk, 0, stream>>>(kb, sa_rot, bkb);
    sort_k<<<BH_, blk, 0, stream>>>(bqb, pqb);
    sort_k<<<BH_, blk, 0, stream>>>(bkb, pkb);
    attn_k<float,float><<<BH_ * NC_, blk, 0, stream>>>(qb, kb, vb, bqb, bkb, pqb, pkb, ob);
    gemm_k<0,1><<<g512, blk, 0, stream>>>(ob, sa_Wo, dec, act0, 512, 512);
    ln_k<true><<<M_, blk, 0, stream>>>(act0, sa_g, sa_b, act0, act0bf);

    // ---------------- cross-attention ----------------
    gemm_k<0,0><<<g256, blk, 0, stream>>>(act0, wrotq, nullptr, rq, 256, 512);
    gemm_k<0,0><<<g256, blk, 0, stream>>>(enc,  wrotk, nullptr, rk, 256, 512);
    amax_k<<<M_ * 8 / 256, blk, 0, stream>>>(rq, bqb);
    amax_k<<<M_ * 8 / 256, blk, 0, stream>>>(rk, bkb);
    sort_k<<<BH_, blk, 0, stream>>>(bqb, pqb);
    sort_k<<<BH_, blk, 0, stream>>>(bkb, pkb);
    cast_k<<<M_ * 512 / 1024, blk, 0, stream>>>(enc, encbf);
    mgemm_k<2,0,false,false><<<g512, blk, 0, stream>>>((const short*)act0bf, (const short*)caWqt, nullptr, nullptr, cq, 512, 512);
    mgemm_k<2,0,false,false><<<g512, blk, 0, stream>>>((const short*)encbf, (const short*)caWkt, nullptr, nullptr, ck, 512, 512);
    mgemm_k<2,0,false,false><<<g512, blk, 0, stream>>>((const short*)encbf, (const short*)caWvt, nullptr, nullptr, cv, 512, 512);
    attn_k<bf16,bf16><<<BH_ * NC_, blk, 0, stream>>>(cq, ck, cv, bqb, bkb, pqb, pkb, caOut);
    mgemm_k<0,1,false,false><<<g512, blk, 0, stream>>>((const short*)caOut, (const short*)caWot, nullptr, act0, act1, 512, 512);
    ln_k<true><<<M_, blk, 0, stream>>>(act1, ca_g, ca_b, act1, act1bf);

    // ---------------- feed-forward ----------------
    mgemm_k<1,0,true,true><<<g2048, blk, 0, stream>>>((const short*)act1bf, (const short*)ffW1t, ff_b1, nullptr, hid, 2048, 512);
    mgemm_k<0,1,true,false><<<g512, blk, 0, stream>>>((const short*)hid, (const short*)ffW2t, ff_b2, act1, ffout, 512, 2048);
    ln_k<false><<<M_, blk, 0, stream>>>(ffout, ff_g, ff_b, (float*)d_out, nullptr);
}